// Round 15
// baseline (88.660 us; speedup 1.0000x reference)
//
#include <hip/hip_runtime.h>
#include <math.h>

// BDH recurrence, 7-kernel pipeline (round-11 base + xscan coalescing +
// split-K-semaphore-fused final LN). fp16 MFMA GEMMs, f32 accum.
//  K1 cvt(emb,E,Dx,Dy)->f16 + LN^T(emb)->f16 + zero cnt           1408
//  K2 xu = relu(emb @ Dx^T) -> f16 + rowsum partials              (8,32)
//  K3 x-scan (8 chunks x 32 j, 64B segments)                      256
//  K4 W = causal-decay mask . (X X^T)  batched                    (4,4,8)
//  K5 aln = LN(W @ lnv), 16-row blocks (grid 128)                 (16,8)
//  K6 y = relu(aln @ Dy^T) * x                                    (8,32)
//  K7 vpart = y @ E^T split-K=2; 8th block per row-group does LN  (4,32,2)

#define TT 256
#define BB 8
#define DD 256
#define NN 1024
#define ROWS (BB*TT)   // 2048

using f16   = _Float16;
using f16x4 = __attribute__((ext_vector_type(4))) _Float16;
using f16x8 = __attribute__((ext_vector_type(8))) _Float16;
using f32x4 = __attribute__((ext_vector_type(4))) float;

__device__ inline f32x4 mfma16(f16x8 a, f16x8 b, f32x4 c) {
    return __builtin_amdgcn_mfma_f32_16x16x32_f16(a, b, c, 0, 0, 0);
}

// ===== K1: convert inputs to fp16 + LN-transpose of emb + zero cnt =========
__launch_bounds__(256)
__global__ void cvtln_kernel(const float* __restrict__ emb, const float* __restrict__ E,
                             const float* __restrict__ Dx, const float* __restrict__ Dy,
                             f16* __restrict__ embf, f16* __restrict__ Ef,
                             f16* __restrict__ Dxf, f16* __restrict__ Dyf,
                             f16* __restrict__ lnvTf, int* __restrict__ cnt) {
    __shared__ f16 sT[256][24];
    if (blockIdx.x == 0 && threadIdx.x < 32) cnt[threadIdx.x] = 0;
    if (blockIdx.x < 1280) {
        int base = (blockIdx.x * 256 + threadIdx.x) * 4;
        const float* s; f16* d; int loc;
        if      (base <  524288) { s = emb; d = embf; loc = base; }
        else if (base <  786432) { s = E;   d = Ef;   loc = base - 524288; }
        else if (base < 1048576) { s = Dx;  d = Dxf;  loc = base - 786432; }
        else                     { s = Dy;  d = Dyf;  loc = base - 1048576; }
        float4 v = *(const float4*)(s + loc);
        f16x4 h = {(f16)v.x, (f16)v.y, (f16)v.z, (f16)v.w};
        *(f16x4*)(d + loc) = h;
        return;
    }
    const int bx = blockIdx.x - 1280;
    const int b  = bx >> 4;
    const int t0 = (bx & 15) * 16;
    const int wave = threadIdx.x >> 6;
    const int lane = threadIdx.x & 63;
#pragma unroll
    for (int rr = 0; rr < 4; ++rr) {
        int tloc = wave * 4 + rr;
        const float* p = emb + ((size_t)b * TT + t0 + tloc) * DD;
        float4 v = *(const float4*)(p + lane * 4);
        float s  = v.x + v.y + v.z + v.w;
        float s2 = v.x*v.x + v.y*v.y + v.z*v.z + v.w*v.w;
#pragma unroll
        for (int o = 32; o; o >>= 1) {
            s  += __shfl_xor(s,  o, 64);
            s2 += __shfl_xor(s2, o, 64);
        }
        float m   = s * (1.0f / 256.0f);
        float sc  = rsqrtf(s2 * (1.0f / 256.0f) - m * m + 1e-5f);
        sT[lane * 4 + 0][tloc] = (f16)((v.x - m) * sc);
        sT[lane * 4 + 1][tloc] = (f16)((v.y - m) * sc);
        sT[lane * 4 + 2][tloc] = (f16)((v.z - m) * sc);
        sT[lane * 4 + 3][tloc] = (f16)((v.w - m) * sc);
    }
    __syncthreads();
    int j = threadIdx.x;
    size_t o = ((size_t)b * DD + j) * TT + t0;
    *(f16x8*)(lnvTf + o)     = *(const f16x8*)&sT[j][0];
    *(f16x8*)(lnvTf + o + 8) = *(const f16x8*)&sT[j][8];
}

// ===== K2: xu = relu(emb @ Dx^T) -> f16, 64x128 tile, + Spart ==============
__launch_bounds__(256)
__global__ void k_xu(const f16* __restrict__ A, const f16* __restrict__ B,
                     f16* __restrict__ xuh, float* __restrict__ Spart) {
    const int i0 = blockIdx.y * 64, j0 = blockIdx.x * 128;
    const int t = threadIdx.x, lane = t & 63, wid = t >> 6;
    const int wr = wid >> 1, wc = wid & 1;
    const int lr = lane >> 4, lc = lane & 15;
    __shared__ __align__(16) f16 sA[2][64][40], sB[2][128][40];
    __shared__ float ssum[64][2];
    const int arow = t >> 2, akq = (t & 3) * 8;
    f32x4 acc[2][4];
    const f32x4 z4 = {0.f, 0.f, 0.f, 0.f};
#pragma unroll
    for (int fi = 0; fi < 2; ++fi)
#pragma unroll
        for (int fj = 0; fj < 4; ++fj) acc[fi][fj] = z4;

    const int NT = DD / 32;  // 8
    const f16* pa  = A + (size_t)(i0 + arow) * DD + akq;
    const f16* pb0 = B + (size_t)(j0 + arow) * DD + akq;
    const f16* pb1 = B + (size_t)(j0 + 64 + arow) * DD + akq;
    f16x8 va  = *(const f16x8*)pa;
    f16x8 vb0 = *(const f16x8*)pb0;
    f16x8 vb1 = *(const f16x8*)pb1;
    *(f16x8*)&sA[0][arow][akq]      = va;
    *(f16x8*)&sB[0][arow][akq]      = vb0;
    *(f16x8*)&sB[0][64 + arow][akq] = vb1;
    __syncthreads();
    int cur = 0;
    for (int kt = 0; kt < NT; ++kt) {
        if (kt + 1 < NT) {
            int ko = (kt + 1) * 32;
            va  = *(const f16x8*)(pa + ko);
            vb0 = *(const f16x8*)(pb0 + ko);
            vb1 = *(const f16x8*)(pb1 + ko);
        }
        f16x8 ah[2], bh[4];
#pragma unroll
        for (int fi = 0; fi < 2; ++fi)
            ah[fi] = *(const f16x8*)&sA[cur][wr * 32 + fi * 16 + lc][lr * 8];
#pragma unroll
        for (int fj = 0; fj < 4; ++fj)
            bh[fj] = *(const f16x8*)&sB[cur][wc * 64 + fj * 16 + lc][lr * 8];
#pragma unroll
        for (int fi = 0; fi < 2; ++fi)
#pragma unroll
            for (int fj = 0; fj < 4; ++fj)
                acc[fi][fj] = mfma16(ah[fi], bh[fj], acc[fi][fj]);
        if (kt + 1 < NT) {
            *(f16x8*)&sA[cur ^ 1][arow][akq]      = va;
            *(f16x8*)&sB[cur ^ 1][arow][akq]      = vb0;
            *(f16x8*)&sB[cur ^ 1][64 + arow][akq] = vb1;
            __syncthreads();
            cur ^= 1;
        }
    }
    float rs[2][4] = {};
#pragma unroll
    for (int fi = 0; fi < 2; ++fi)
#pragma unroll
        for (int fj = 0; fj < 4; ++fj) {
            f32x4 d = acc[fi][fj];
#pragma unroll
            for (int r = 0; r < 4; ++r) {
                int i = i0 + wr * 32 + fi * 16 + lr * 4 + r;
                int j = j0 + wc * 64 + fj * 16 + lc;
                float vv = fmaxf(d[r], 0.f);
                xuh[(size_t)i * NN + j] = (f16)vv;
                rs[fi][r] += vv;
            }
        }
#pragma unroll
    for (int fi = 0; fi < 2; ++fi)
#pragma unroll
        for (int r = 0; r < 4; ++r) {
            float v = rs[fi][r];
#pragma unroll
            for (int m = 1; m < 16; m <<= 1) v += __shfl_xor(v, m, 64);
            if (lc == 0) ssum[wr * 32 + fi * 16 + lr * 4 + r][wc] = v;
        }
    __syncthreads();
    if (t < 64) Spart[(size_t)blockIdx.x * ROWS + i0 + t] = ssum[t][0] + ssum[t][1];
}

// ===== K3: x-scan, 8 chunks x 32 j (64B segments), inline normalizer =======
__launch_bounds__(256)
__global__ void k_xscan(const f16* __restrict__ xuh, const float* __restrict__ Spart,
                        f16* __restrict__ xf) {
    __shared__ float Gs[8][33], Hs[8][33], Cs[8][33];
    __shared__ float sS[256], sRC[256];
    __shared__ int bad;
    const int b = blockIdx.x >> 5, jgrp = blockIdx.x & 31;
    const int tid = threadIdx.x;
    float s = 0.f;
#pragma unroll
    for (int g = 0; g < 8; ++g) s += Spart[(size_t)g * ROWS + b * TT + tid];
    if (tid == 0) bad = 0;
    sS[tid] = s;
    __syncthreads();
    float us = (tid == 0) ? s : (0.97f + s);
    if (us < 1e-12f) bad = 1;
    __syncthreads();
    if (!bad) {
        sRC[tid] = 1.0f / us;
    } else if (tid == 0) {
        float sigma = 0.f;
        for (int tt = 0; tt < TT; ++tt) {
            float u2 = fmaf(0.97f, sigma, sS[tt]);
            float r  = 1.0f / fmaxf(u2, 1e-12f);
            sRC[tt] = r;
            sigma = u2 * r;
        }
    }
    __syncthreads();

    const int ck = tid >> 5, jl = tid & 31;
    const int j  = jgrp * 32 + jl;
    const size_t base = ((size_t)b * TT + ck * 32) * NN + j;
    float xur[32], rcr[32];
#pragma unroll
    for (int i = 0; i < 32; ++i) xur[i] = (float)xuh[base + (size_t)i * NN];
#pragma unroll
    for (int i = 0; i < 32; ++i) rcr[i] = sRC[ck * 32 + i];
    float xs = 0.f, G = 1.f;
#pragma unroll
    for (int i = 0; i < 32; ++i) {
        xs = fmaf(0.97f, xs, xur[i]) * rcr[i];
        G *= 0.97f * rcr[i];
    }
    Gs[ck][jl] = G;
    Hs[ck][jl] = xs;
    __syncthreads();
    if (tid < 32) {
        float cr = 0.f;
        Cs[0][tid] = 0.f;
#pragma unroll
        for (int cc = 0; cc < 7; ++cc) {
            cr = fmaf(Gs[cc][tid], cr, Hs[cc][tid]);
            Cs[cc + 1][tid] = cr;
        }
    }
    __syncthreads();
    xs = Cs[ck][jl];
#pragma unroll
    for (int i = 0; i < 32; ++i) {
        xs = fmaf(0.97f, xs, xur[i]) * rcr[i];
        xf[base + (size_t)i * NN] = (f16)xs;
    }
}

// ===== K4: W = causal-decay mask . (X X^T), 64x64, batched (r11 staged) ====
__launch_bounds__(256)
__global__ void k_W(const f16* __restrict__ xf, f16* __restrict__ Wf) {
    const int b = blockIdx.z;
    const f16* X = xf + (size_t)b * TT * NN;
    f16* Wb = Wf + (size_t)b * TT * TT;
    const int i0 = blockIdx.y * 64, j0 = blockIdx.x * 64;
    const int t = threadIdx.x, lane = t & 63, wid = t >> 6;
    const int wr = wid >> 1, wc = wid & 1;
    const int lr = lane >> 4, lc = lane & 15;
    const float L2D = -0.043943348f;  // log2(0.97)

    if (j0 > i0) {
#pragma unroll
        for (int fi = 0; fi < 2; ++fi)
#pragma unroll
            for (int fj = 0; fj < 2; ++fj)
#pragma unroll
                for (int r = 0; r < 4; ++r) {
                    int i = i0 + wr * 32 + fi * 16 + lr * 4 + r;
                    int j = j0 + wc * 32 + fj * 16 + lc;
                    Wb[(size_t)i * TT + j] = (f16)0.f;
                }
        return;
    }

    __shared__ __align__(16) f16 sA[2][64][40], sB[2][64][40];
    const int srow = t >> 2, skq = (t & 3) * 8;
    f32x4 acc[2][2];
    const f32x4 z4 = {0.f, 0.f, 0.f, 0.f};
    acc[0][0] = z4; acc[0][1] = z4; acc[1][0] = z4; acc[1][1] = z4;

    const int NT = NN / 32;  // 32
    const f16* pa = X + (size_t)(i0 + srow) * NN + skq;
    const f16* pb = X + (size_t)(j0 + srow) * NN + skq;
    f16x8 va = *(const f16x8*)pa;
    f16x8 vb = *(const f16x8*)pb;
    *(f16x8*)&sA[0][srow][skq] = va;
    *(f16x8*)&sB[0][srow][skq] = vb;
    __syncthreads();
    int cur = 0;
    for (int kt = 0; kt < NT; ++kt) {
        if (kt + 1 < NT) {
            va = *(const f16x8*)(pa + (kt + 1) * 32);
            vb = *(const f16x8*)(pb + (kt + 1) * 32);
        }
        f16x8 ah0 = *(const f16x8*)&sA[cur][wr * 32 + lc][lr * 8];
        f16x8 ah1 = *(const f16x8*)&sA[cur][wr * 32 + 16 + lc][lr * 8];
        f16x8 bh0 = *(const f16x8*)&sB[cur][wc * 32 + lc][lr * 8];
        f16x8 bh1 = *(const f16x8*)&sB[cur][wc * 32 + 16 + lc][lr * 8];
        acc[0][0] = mfma16(ah0, bh0, acc[0][0]);
        acc[0][1] = mfma16(ah0, bh1, acc[0][1]);
        acc[1][0] = mfma16(ah1, bh0, acc[1][0]);
        acc[1][1] = mfma16(ah1, bh1, acc[1][1]);
        if (kt + 1 < NT) {
            *(f16x8*)&sA[cur ^ 1][srow][skq] = va;
            *(f16x8*)&sB[cur ^ 1][srow][skq] = vb;
            __syncthreads();
            cur ^= 1;
        }
    }
#pragma unroll
    for (int fi = 0; fi < 2; ++fi)
#pragma unroll
        for (int fj = 0; fj < 2; ++fj) {
            f32x4 d = acc[fi][fj];
#pragma unroll
            for (int r = 0; r < 4; ++r) {
                int i = i0 + wr * 32 + fi * 16 + lr * 4 + r;
                int j = j0 + wc * 32 + fj * 16 + lc;
                float w = 0.f;
                if (j < i) w = exp2f((float)(i - 1 - j) * L2D) * d[r];
                Wb[(size_t)i * TT + j] = (f16)w;
            }
        }
}

// ===== K5: aln = LN(W @ lnv), 16-row blocks (grid 16x8 = 128) ==============
__launch_bounds__(256)
__global__ void k_aln(const f16* __restrict__ Wf, const f16* __restrict__ lnvTf,
                      f16* __restrict__ alnf) {
    const int b = blockIdx.y;
    const int i0 = blockIdx.x * 16;
    const f16* A = Wf + (size_t)b * TT * TT;
    const f16* B = lnvTf + (size_t)b * DD * TT;
    const int t = threadIdx.x, lane = t & 63, w = t >> 6;
    const int lr = lane >> 4, lc = lane & 15;
    __shared__ __align__(16) f16 sA[2][16][40], sB[2][256][40];
    __shared__ float sS[4][16], sS2[4][16];
    const int arow = t >> 2, akq = (t & 3) * 8;
    f32x4 acc[4];
    const f32x4 z4 = {0.f, 0.f, 0.f, 0.f};
#pragma unroll
    for (int f = 0; f < 4; ++f) acc[f] = z4;

    const int NT = TT / 32;  // 8
    const f16* pa = A + (size_t)(i0 + arow) * TT + akq;
    const f16* pb = B + (size_t)arow * TT + akq;
    f16x8 va;
    f16x8 vb[4];
    if (t < 64) va = *(const f16x8*)pa;
#pragma unroll
    for (int q = 0; q < 4; ++q)
        vb[q] = *(const f16x8*)(pb + (size_t)q * 64 * TT);
    if (t < 64) *(f16x8*)&sA[0][arow][akq] = va;
#pragma unroll
    for (int q = 0; q < 4; ++q)
        *(f16x8*)&sB[0][q * 64 + arow][akq] = vb[q];
    __syncthreads();
    int cur = 0;
    for (int kt = 0; kt < NT; ++kt) {
        if (kt + 1 < NT) {
            int ko = (kt + 1) * 32;
            if (t < 64) va = *(const f16x8*)(pa + ko);
#pragma unroll
            for (int q = 0; q < 4; ++q)
                vb[q] = *(const f16x8*)(pb + (size_t)q * 64 * TT + ko);
        }
        f16x8 af = *(const f16x8*)&sA[cur][lc][lr * 8];
#pragma unroll
        for (int f = 0; f < 4; ++f) {
            f16x8 bf = *(const f16x8*)&sB[cur][w * 64 + f * 16 + lc][lr * 8];
            acc[f] = mfma16(af, bf, acc[f]);
        }
        if (kt + 1 < NT) {
            if (t < 64) *(f16x8*)&sA[cur ^ 1][arow][akq] = va;
#pragma unroll
            for (int q = 0; q < 4; ++q)
                *(f16x8*)&sB[cur ^ 1][q * 64 + arow][akq] = vb[q];
            __syncthreads();
            cur ^= 1;
        }
    }
    float s[4] = {}, s2[4] = {};
#pragma unroll
    for (int f = 0; f < 4; ++f)
#pragma unroll
        for (int r = 0; r < 4; ++r) { float v = acc[f][r]; s[r] += v; s2[r] += v * v; }
#pragma unroll
    for (int m = 1; m < 16; m <<= 1)
#pragma unroll
        for (int r = 0; r < 4; ++r) {
            s[r]  += __shfl_xor(s[r],  m, 64);
            s2[r] += __shfl_xor(s2[r], m, 64);
        }
    if (lc == 0)
#pragma unroll
        for (int r = 0; r < 4; ++r) { sS[w][lr * 4 + r] = s[r]; sS2[w][lr * 4 + r] = s2[r]; }
    __syncthreads();
    float mean[4], rstd[4];
#pragma unroll
    for (int r = 0; r < 4; ++r) {
        int row = lr * 4 + r;
        float tot  = sS[0][row] + sS[1][row] + sS[2][row] + sS[3][row];
        float tot2 = sS2[0][row] + sS2[1][row] + sS2[2][row] + sS2[3][row];
        mean[r] = tot * (1.f / 256.f);
        rstd[r] = rsqrtf(tot2 * (1.f / 256.f) - mean[r] * mean[r] + 1e-5f);
    }
#pragma unroll
    for (int f = 0; f < 4; ++f)
#pragma unroll
        for (int r = 0; r < 4; ++r) {
            int i = i0 + lr * 4 + r;
            int j = w * 64 + f * 16 + lc;
            alnf[((size_t)b * TT + i) * DD + j] = (f16)((acc[f][r] - mean[r]) * rstd[r]);
        }
}

// ===== K6: y = relu(aln @ Dy^T) * x, 64x128 tile, all f16 ==================
__launch_bounds__(256)
__global__ void k_y(const f16* __restrict__ A, const f16* __restrict__ B,
                    f16* __restrict__ yf, const f16* __restrict__ xf) {
    const int i0 = blockIdx.y * 64, j0 = blockIdx.x * 128;
    const int t = threadIdx.x, lane = t & 63, wid = t >> 6;
    const int wr = wid >> 1, wc = wid & 1;
    const int lr = lane >> 4, lc = lane & 15;
    __shared__ __align__(16) f16 sA[2][64][40], sB[2][128][40];
    const int arow = t >> 2, akq = (t & 3) * 8;
    f32x4 acc[2][4];
    const f32x4 z4 = {0.f, 0.f, 0.f, 0.f};
#pragma unroll
    for (int fi = 0; fi < 2; ++fi)
#pragma unroll
        for (int fj = 0; fj < 4; ++fj) acc[fi][fj] = z4;

    const int NT = DD / 32;  // 8
    const f16* pa  = A + (size_t)(i0 + arow) * DD + akq;
    const f16* pb0 = B + (size_t)(j0 + arow) * DD + akq;
    const f16* pb1 = B + (size_t)(j0 + 64 + arow) * DD + akq;
    f16x8 va  = *(const f16x8*)pa;
    f16x8 vb0 = *(const f16x8*)pb0;
    f16x8 vb1 = *(const f16x8*)pb1;
    *(f16x8*)&sA[0][arow][akq]      = va;
    *(f16x8*)&sB[0][arow][akq]      = vb0;
    *(f16x8*)&sB[0][64 + arow][akq] = vb1;
    __syncthreads();
    int cur = 0;
    for (int kt = 0; kt < NT; ++kt) {
        if (kt + 1 < NT) {
            int ko = (kt + 1) * 32;
            va  = *(const f16x8*)(pa + ko);
            vb0 = *(const f16x8*)(pb0 + ko);
            vb1 = *(const f16x8*)(pb1 + ko);
        }
        f16x8 ah[2], bh[4];
#pragma unroll
        for (int fi = 0; fi < 2; ++fi)
            ah[fi] = *(const f16x8*)&sA[cur][wr * 32 + fi * 16 + lc][lr * 8];
#pragma unroll
        for (int fj = 0; fj < 4; ++fj)
            bh[fj] = *(const f16x8*)&sB[cur][wc * 64 + fj * 16 + lc][lr * 8];
#pragma unroll
        for (int fi = 0; fi < 2; ++fi)
#pragma unroll
            for (int fj = 0; fj < 4; ++fj)
                acc[fi][fj] = mfma16(ah[fi], bh[fj], acc[fi][fj]);
        if (kt + 1 < NT) {
            *(f16x8*)&sA[cur ^ 1][arow][akq]      = va;
            *(f16x8*)&sB[cur ^ 1][arow][akq]      = vb0;
            *(f16x8*)&sB[cur ^ 1][64 + arow][akq] = vb1;
            __syncthreads();
            cur ^= 1;
        }
    }
#pragma unroll
    for (int fi = 0; fi < 2; ++fi)
#pragma unroll
        for (int fj = 0; fj < 4; ++fj) {
            f32x4 d = acc[fi][fj];
#pragma unroll
            for (int r = 0; r < 4; ++r) {
                int i = i0 + wr * 32 + fi * 16 + lr * 4 + r;
                int j = j0 + wc * 64 + fj * 16 + lc;
                size_t o = (size_t)i * NN + j;
                float vv = fmaxf(d[r], 0.f) * (float)xf[o];
                yf[o] = (f16)vv;
            }
        }
}

// ===== K7: vpart[z] = y @ E^T split-K=2; 8th block per 64-row group LNs ====
__launch_bounds__(256)
__global__ void k_vg(const f16* __restrict__ yf, const f16* __restrict__ Ef,
                     float* __restrict__ vpart, int* __restrict__ cnt,
                     float* __restrict__ out) {
    const int z = blockIdx.z;
    float* C = vpart + (size_t)z * ROWS * DD;
    const int i0 = blockIdx.y * 64, j0 = blockIdx.x * 64;
    const int t = threadIdx.x, lane = t & 63, wid = t >> 6;
    const int wr = wid >> 1, wc = wid & 1;
    const int lr = lane >> 4, lc = lane & 15;
    __shared__ __align__(16) f16 sA[2][64][40], sB[2][64][40];
    __shared__ int lastFlag;
    const int srow = t >> 2, skq = (t & 3) * 8;
    f32x4 acc[2][2];
    const f32x4 z4 = {0.f, 0.f, 0.f, 0.f};
    acc[0][0] = z4; acc[0][1] = z4; acc[1][0] = z4; acc[1][1] = z4;

    const int NT = 512 / 32;  // 16
    const f16* pa = yf + (size_t)(i0 + srow) * NN + z * 512 + skq;
    const f16* pb = Ef + (size_t)(j0 + srow) * NN + z * 512 + skq;
    f16x8 va = *(const f16x8*)pa;
    f16x8 vb = *(const f16x8*)pb;
    *(f16x8*)&sA[0][srow][skq] = va;
    *(f16x8*)&sB[0][srow][skq] = vb;
    __syncthreads();
    int cur = 0;
    for (int kt = 0; kt < NT; ++kt) {
        if (kt + 1 < NT) {
            va = *(const f16x8*)(pa + (kt + 1) * 32);
            vb = *(const f16x8*)(pb + (kt + 1) * 32);
        }
        f16x8 ah0 = *(const f16x8*)&sA[cur][wr * 32 + lc][lr * 8];
        f16x8 ah1 = *(const f16x8*)&sA[cur][wr * 32 + 16 + lc][lr * 8];
        f16x8 bh0 = *(const f16x8*)&sB[cur][wc * 32 + lc][lr * 8];
        f16x8 bh1 = *(const f16x8*)&sB[cur][wc * 32 + 16 + lc][lr * 8];
        acc[0][0] = mfma16(ah0, bh0, acc[0][0]);
        acc[0][1] = mfma16(ah0, bh1, acc[0][1]);
        acc[1][0] = mfma16(ah1, bh0, acc[1][0]);
        acc[1][1] = mfma16(ah1, bh1, acc[1][1]);
        if (kt + 1 < NT) {
            *(f16x8*)&sA[cur ^ 1][srow][skq] = va;
            *(f16x8*)&sB[cur ^ 1][srow][skq] = vb;
            __syncthreads();
            cur ^= 1;
        }
    }
#pragma unroll
    for (int fi = 0; fi < 2; ++fi)
#pragma unroll
        for (int fj = 0; fj < 2; ++fj) {
            f32x4 d = acc[fi][fj];
#pragma unroll
            for (int r = 0; r < 4; ++r) {
                int i = i0 + wr * 32 + fi * 16 + lr * 4 + r;
                int j = j0 + wc * 32 + fj * 16 + lc;
                C[(size_t)i * DD + j] = d[r];
            }
        }

    // split-K semaphore: 8 contributors (4 j-tiles x 2 z) per 64-row group.
    __threadfence();
    if (t == 0) {
        int old = atomicAdd(&cnt[blockIdx.y], 1);
        lastFlag = (old == 7);
    }
    __syncthreads();
    if (!lastFlag) return;
    __threadfence();  // acquire: all partials visible
#pragma unroll
    for (int u = 0; u < 16; ++u) {
        int row = i0 + u * 4 + wid;
        float4 v = *(const float4*)(vpart + (size_t)row * DD + lane * 4);
        float4 w = *(const float4*)(vpart + (size_t)(ROWS + row) * DD + lane * 4);
        v.x += w.x; v.y += w.y; v.z += w.z; v.w += w.w;
        float s  = v.x + v.y + v.z + v.w;
        float s2 = v.x*v.x + v.y*v.y + v.z*v.z + v.w*v.w;
#pragma unroll
        for (int o = 32; o; o >>= 1) {
            s  += __shfl_xor(s,  o, 64);
            s2 += __shfl_xor(s2, o, 64);
        }
        float m  = s * (1.0f / 256.0f);
        float sc = rsqrtf(s2 * (1.0f / 256.0f) - m * m + 1e-5f);
        float4 o4 = {(v.x - m) * sc, (v.y - m) * sc, (v.z - m) * sc, (v.w - m) * sc};
        *(float4*)(out + (size_t)row * DD + lane * 4) = o4;
    }
}

extern "C" void kernel_launch(void* const* d_in, const int* in_sizes, int n_in,
                              void* d_out, int out_size, void* d_ws, size_t ws_size,
                              hipStream_t stream) {
    (void)in_sizes; (void)n_in; (void)out_size; (void)ws_size;
    const float* emb = (const float*)d_in[0];   // (B,T,d)
    const float* E   = (const float*)d_in[1];   // (d,n)
    const float* Dx  = (const float*)d_in[2];   // (n,d)
    const float* Dy  = (const float*)d_in[3];   // (n,d)
    float* out = (float*)d_out;                 // (B,T,d)

    char* wsb = (char*)d_ws;
    f16*   embf  = (f16*)(wsb + 0);          // 1 MB
    f16*   Ef    = (f16*)(wsb + 1048576);    // 512 KB
    f16*   Dxf   = (f16*)(wsb + 1572864);    // 512 KB
    f16*   Dyf   = (f16*)(wsb + 2097152);    // 512 KB
    f16*   lnvTf = (f16*)(wsb + 2621440);    // 1 MB   [b][j][t]
    f16*   xuh   = (f16*)(wsb + 3670016);    // 4 MB
    f16*   xf    = (f16*)(wsb + 7864320);    // 4 MB
    f16*   Wf    = (f16*)(wsb + 12058624);   // 1 MB
    f16*   alnf  = (f16*)(wsb + 13107200);   // 1 MB
    f16*   yf    = (f16*)(wsb + 14155776);   // 4 MB
    float* vpart = (float*)(wsb + 18350080); // 4 MB (2 x ROWS*DD)
    float* Spart = (float*)(wsb + 22544384); // 64 KB (8 x ROWS)
    int*   cnt   = (int*)(wsb + 22609920);   // 128 B (32 counters)

    // K1: f16 conversions + LN^T(emb) + zero cnt
    cvtln_kernel<<<1280 + ROWS / 16, 256, 0, stream>>>(
        emb, E, Dx, Dy, embf, Ef, Dxf, Dyf, lnvTf, cnt);
    // K2: xu = relu(emb @ Dx^T) -> f16 + row-sum partials
    k_xu<<<dim3(NN / 128, ROWS / 64), 256, 0, stream>>>(embf, Dxf, xuh, Spart);
    // K3: x scan (coalesced 8x32 mapping)
    k_xscan<<<BB * 32, 256, 0, stream>>>(xuh, Spart, xf);
    // K4: W = mask . (X X^T)
    k_W<<<dim3(TT / 64, TT / 64, BB), 256, 0, stream>>>(xf, Wf);
    // K5: aln = LN(W @ lnv), 16-row blocks
    k_aln<<<dim3(TT / 16, BB), 256, 0, stream>>>(Wf, lnvTf, alnf);
    // K6: y = relu(aln @ Dy^T) * x
    k_y<<<dim3(NN / 128, ROWS / 64), 256, 0, stream>>>(alnf, Dyf, yf, xf);
    // K7: vpart = y @ E^T split-K=2 + semaphore-fused final LN
    k_vg<<<dim3(DD / 64, ROWS / 64, 2), 256, 0, stream>>>(yf, Ef, vpart, cnt, out);
}

// Round 16
// 57.864 us; speedup vs baseline: 1.5322x; 1.5322x over previous
//
#include <hip/hip_runtime.h>
#include <math.h>

// BDH recurrence, 8-kernel pipeline (round-11 measured-best base + coalesced
// x-scan). fp16 MFMA GEMMs (f32 accum), all GEMM operands pre-converted f16.
//  K1 cvt(emb,E,Dx,Dy)->f16 + LN^T(emb)->f16                      1408
//  K2 xu = relu(emb @ Dx^T) -> f16 + rowsum partials              (8,32)
//  K3 x-scan (8 chunks x 32 j, 64B segments)                      256
//  K4 W = causal-decay mask . (X X^T)  batched                    (4,4,8)
//  K5 aln = LN(W @ lnv), 16-row blocks (grid 128)                 (16,8)
//  K6 y = relu(aln @ Dy^T) * x                                    (8,32)
//  K7 vpart = y @ E^T  split-K=2                                  (4,32,2)
//  K8 out = LN(vpart0+vpart1)                                     512

#define TT 256
#define BB 8
#define DD 256
#define NN 1024
#define ROWS (BB*TT)   // 2048

using f16   = _Float16;
using f16x4 = __attribute__((ext_vector_type(4))) _Float16;
using f16x8 = __attribute__((ext_vector_type(8))) _Float16;
using f32x4 = __attribute__((ext_vector_type(4))) float;

__device__ inline f32x4 mfma16(f16x8 a, f16x8 b, f32x4 c) {
    return __builtin_amdgcn_mfma_f32_16x16x32_f16(a, b, c, 0, 0, 0);
}

// ===== K1: convert inputs to fp16 + LN-transpose of emb ====================
__launch_bounds__(256)
__global__ void cvtln_kernel(const float* __restrict__ emb, const float* __restrict__ E,
                             const float* __restrict__ Dx, const float* __restrict__ Dy,
                             f16* __restrict__ embf, f16* __restrict__ Ef,
                             f16* __restrict__ Dxf, f16* __restrict__ Dyf,
                             f16* __restrict__ lnvTf) {
    __shared__ f16 sT[256][24];
    if (blockIdx.x < 1280) {
        int base = (blockIdx.x * 256 + threadIdx.x) * 4;
        const float* s; f16* d; int loc;
        if      (base <  524288) { s = emb; d = embf; loc = base; }
        else if (base <  786432) { s = E;   d = Ef;   loc = base - 524288; }
        else if (base < 1048576) { s = Dx;  d = Dxf;  loc = base - 786432; }
        else                     { s = Dy;  d = Dyf;  loc = base - 1048576; }
        float4 v = *(const float4*)(s + loc);
        f16x4 h = {(f16)v.x, (f16)v.y, (f16)v.z, (f16)v.w};
        *(f16x4*)(d + loc) = h;
        return;
    }
    const int bx = blockIdx.x - 1280;
    const int b  = bx >> 4;
    const int t0 = (bx & 15) * 16;
    const int wave = threadIdx.x >> 6;
    const int lane = threadIdx.x & 63;
#pragma unroll
    for (int rr = 0; rr < 4; ++rr) {
        int tloc = wave * 4 + rr;
        const float* p = emb + ((size_t)b * TT + t0 + tloc) * DD;
        float4 v = *(const float4*)(p + lane * 4);
        float s  = v.x + v.y + v.z + v.w;
        float s2 = v.x*v.x + v.y*v.y + v.z*v.z + v.w*v.w;
#pragma unroll
        for (int o = 32; o; o >>= 1) {
            s  += __shfl_xor(s,  o, 64);
            s2 += __shfl_xor(s2, o, 64);
        }
        float m   = s * (1.0f / 256.0f);
        float sc  = rsqrtf(s2 * (1.0f / 256.0f) - m * m + 1e-5f);
        sT[lane * 4 + 0][tloc] = (f16)((v.x - m) * sc);
        sT[lane * 4 + 1][tloc] = (f16)((v.y - m) * sc);
        sT[lane * 4 + 2][tloc] = (f16)((v.z - m) * sc);
        sT[lane * 4 + 3][tloc] = (f16)((v.w - m) * sc);
    }
    __syncthreads();
    int j = threadIdx.x;
    size_t o = ((size_t)b * DD + j) * TT + t0;
    *(f16x8*)(lnvTf + o)     = *(const f16x8*)&sT[j][0];
    *(f16x8*)(lnvTf + o + 8) = *(const f16x8*)&sT[j][8];
}

// ===== K2: xu = relu(emb @ Dx^T) -> f16, 64x128 tile, + Spart ==============
__launch_bounds__(256)
__global__ void k_xu(const f16* __restrict__ A, const f16* __restrict__ B,
                     f16* __restrict__ xuh, float* __restrict__ Spart) {
    const int i0 = blockIdx.y * 64, j0 = blockIdx.x * 128;
    const int t = threadIdx.x, lane = t & 63, wid = t >> 6;
    const int wr = wid >> 1, wc = wid & 1;
    const int lr = lane >> 4, lc = lane & 15;
    __shared__ __align__(16) f16 sA[2][64][40], sB[2][128][40];
    __shared__ float ssum[64][2];
    const int arow = t >> 2, akq = (t & 3) * 8;
    f32x4 acc[2][4];
    const f32x4 z4 = {0.f, 0.f, 0.f, 0.f};
#pragma unroll
    for (int fi = 0; fi < 2; ++fi)
#pragma unroll
        for (int fj = 0; fj < 4; ++fj) acc[fi][fj] = z4;

    const int NT = DD / 32;  // 8
    const f16* pa  = A + (size_t)(i0 + arow) * DD + akq;
    const f16* pb0 = B + (size_t)(j0 + arow) * DD + akq;
    const f16* pb1 = B + (size_t)(j0 + 64 + arow) * DD + akq;
    f16x8 va  = *(const f16x8*)pa;
    f16x8 vb0 = *(const f16x8*)pb0;
    f16x8 vb1 = *(const f16x8*)pb1;
    *(f16x8*)&sA[0][arow][akq]      = va;
    *(f16x8*)&sB[0][arow][akq]      = vb0;
    *(f16x8*)&sB[0][64 + arow][akq] = vb1;
    __syncthreads();
    int cur = 0;
    for (int kt = 0; kt < NT; ++kt) {
        if (kt + 1 < NT) {
            int ko = (kt + 1) * 32;
            va  = *(const f16x8*)(pa + ko);
            vb0 = *(const f16x8*)(pb0 + ko);
            vb1 = *(const f16x8*)(pb1 + ko);
        }
        f16x8 ah[2], bh[4];
#pragma unroll
        for (int fi = 0; fi < 2; ++fi)
            ah[fi] = *(const f16x8*)&sA[cur][wr * 32 + fi * 16 + lc][lr * 8];
#pragma unroll
        for (int fj = 0; fj < 4; ++fj)
            bh[fj] = *(const f16x8*)&sB[cur][wc * 64 + fj * 16 + lc][lr * 8];
#pragma unroll
        for (int fi = 0; fi < 2; ++fi)
#pragma unroll
            for (int fj = 0; fj < 4; ++fj)
                acc[fi][fj] = mfma16(ah[fi], bh[fj], acc[fi][fj]);
        if (kt + 1 < NT) {
            *(f16x8*)&sA[cur ^ 1][arow][akq]      = va;
            *(f16x8*)&sB[cur ^ 1][arow][akq]      = vb0;
            *(f16x8*)&sB[cur ^ 1][64 + arow][akq] = vb1;
            __syncthreads();
            cur ^= 1;
        }
    }
    float rs[2][4] = {};
#pragma unroll
    for (int fi = 0; fi < 2; ++fi)
#pragma unroll
        for (int fj = 0; fj < 4; ++fj) {
            f32x4 d = acc[fi][fj];
#pragma unroll
            for (int r = 0; r < 4; ++r) {
                int i = i0 + wr * 32 + fi * 16 + lr * 4 + r;
                int j = j0 + wc * 64 + fj * 16 + lc;
                float vv = fmaxf(d[r], 0.f);
                xuh[(size_t)i * NN + j] = (f16)vv;
                rs[fi][r] += vv;
            }
        }
#pragma unroll
    for (int fi = 0; fi < 2; ++fi)
#pragma unroll
        for (int r = 0; r < 4; ++r) {
            float v = rs[fi][r];
#pragma unroll
            for (int m = 1; m < 16; m <<= 1) v += __shfl_xor(v, m, 64);
            if (lc == 0) ssum[wr * 32 + fi * 16 + lr * 4 + r][wc] = v;
        }
    __syncthreads();
    if (t < 64) Spart[(size_t)blockIdx.x * ROWS + i0 + t] = ssum[t][0] + ssum[t][1];
}

// ===== K3: x-scan, 8 chunks x 32 j (64B segments), inline normalizer =======
__launch_bounds__(256)
__global__ void k_xscan(const f16* __restrict__ xuh, const float* __restrict__ Spart,
                        f16* __restrict__ xf) {
    __shared__ float Gs[8][33], Hs[8][33], Cs[8][33];
    __shared__ float sS[256], sRC[256];
    __shared__ int bad;
    const int b = blockIdx.x >> 5, jgrp = blockIdx.x & 31;
    const int tid = threadIdx.x;
    float s = 0.f;
#pragma unroll
    for (int g = 0; g < 8; ++g) s += Spart[(size_t)g * ROWS + b * TT + tid];
    if (tid == 0) bad = 0;
    sS[tid] = s;
    __syncthreads();
    float us = (tid == 0) ? s : (0.97f + s);
    if (us < 1e-12f) bad = 1;
    __syncthreads();
    if (!bad) {
        sRC[tid] = 1.0f / us;
    } else if (tid == 0) {
        float sigma = 0.f;
        for (int tt = 0; tt < TT; ++tt) {
            float u2 = fmaf(0.97f, sigma, sS[tt]);
            float r  = 1.0f / fmaxf(u2, 1e-12f);
            sRC[tt] = r;
            sigma = u2 * r;
        }
    }
    __syncthreads();

    const int ck = tid >> 5, jl = tid & 31;
    const int j  = jgrp * 32 + jl;
    const size_t base = ((size_t)b * TT + ck * 32) * NN + j;
    float xur[32], rcr[32];
#pragma unroll
    for (int i = 0; i < 32; ++i) xur[i] = (float)xuh[base + (size_t)i * NN];
#pragma unroll
    for (int i = 0; i < 32; ++i) rcr[i] = sRC[ck * 32 + i];
    float xs = 0.f, G = 1.f;
#pragma unroll
    for (int i = 0; i < 32; ++i) {
        xs = fmaf(0.97f, xs, xur[i]) * rcr[i];
        G *= 0.97f * rcr[i];
    }
    Gs[ck][jl] = G;
    Hs[ck][jl] = xs;
    __syncthreads();
    if (tid < 32) {
        float cr = 0.f;
        Cs[0][tid] = 0.f;
#pragma unroll
        for (int cc = 0; cc < 7; ++cc) {
            cr = fmaf(Gs[cc][tid], cr, Hs[cc][tid]);
            Cs[cc + 1][tid] = cr;
        }
    }
    __syncthreads();
    xs = Cs[ck][jl];
#pragma unroll
    for (int i = 0; i < 32; ++i) {
        xs = fmaf(0.97f, xs, xur[i]) * rcr[i];
        xf[base + (size_t)i * NN] = (f16)xs;
    }
}

// ===== K4: W = causal-decay mask . (X X^T), 64x64, batched =================
__launch_bounds__(256)
__global__ void k_W(const f16* __restrict__ xf, f16* __restrict__ Wf) {
    const int b = blockIdx.z;
    const f16* X = xf + (size_t)b * TT * NN;
    f16* Wb = Wf + (size_t)b * TT * TT;
    const int i0 = blockIdx.y * 64, j0 = blockIdx.x * 64;
    const int t = threadIdx.x, lane = t & 63, wid = t >> 6;
    const int wr = wid >> 1, wc = wid & 1;
    const int lr = lane >> 4, lc = lane & 15;
    const float L2D = -0.043943348f;  // log2(0.97)

    if (j0 > i0) {
#pragma unroll
        for (int fi = 0; fi < 2; ++fi)
#pragma unroll
            for (int fj = 0; fj < 2; ++fj)
#pragma unroll
                for (int r = 0; r < 4; ++r) {
                    int i = i0 + wr * 32 + fi * 16 + lr * 4 + r;
                    int j = j0 + wc * 32 + fj * 16 + lc;
                    Wb[(size_t)i * TT + j] = (f16)0.f;
                }
        return;
    }

    __shared__ __align__(16) f16 sA[2][64][40], sB[2][64][40];
    const int srow = t >> 2, skq = (t & 3) * 8;
    f32x4 acc[2][2];
    const f32x4 z4 = {0.f, 0.f, 0.f, 0.f};
    acc[0][0] = z4; acc[0][1] = z4; acc[1][0] = z4; acc[1][1] = z4;

    const int NT = NN / 32;  // 32
    const f16* pa = X + (size_t)(i0 + srow) * NN + skq;
    const f16* pb = X + (size_t)(j0 + srow) * NN + skq;
    f16x8 va = *(const f16x8*)pa;
    f16x8 vb = *(const f16x8*)pb;
    *(f16x8*)&sA[0][srow][skq] = va;
    *(f16x8*)&sB[0][srow][skq] = vb;
    __syncthreads();
    int cur = 0;
    for (int kt = 0; kt < NT; ++kt) {
        if (kt + 1 < NT) {
            va = *(const f16x8*)(pa + (kt + 1) * 32);
            vb = *(const f16x8*)(pb + (kt + 1) * 32);
        }
        f16x8 ah0 = *(const f16x8*)&sA[cur][wr * 32 + lc][lr * 8];
        f16x8 ah1 = *(const f16x8*)&sA[cur][wr * 32 + 16 + lc][lr * 8];
        f16x8 bh0 = *(const f16x8*)&sB[cur][wc * 32 + lc][lr * 8];
        f16x8 bh1 = *(const f16x8*)&sB[cur][wc * 32 + 16 + lc][lr * 8];
        acc[0][0] = mfma16(ah0, bh0, acc[0][0]);
        acc[0][1] = mfma16(ah0, bh1, acc[0][1]);
        acc[1][0] = mfma16(ah1, bh0, acc[1][0]);
        acc[1][1] = mfma16(ah1, bh1, acc[1][1]);
        if (kt + 1 < NT) {
            *(f16x8*)&sA[cur ^ 1][srow][skq] = va;
            *(f16x8*)&sB[cur ^ 1][srow][skq] = vb;
            __syncthreads();
            cur ^= 1;
        }
    }
#pragma unroll
    for (int fi = 0; fi < 2; ++fi)
#pragma unroll
        for (int fj = 0; fj < 2; ++fj) {
            f32x4 d = acc[fi][fj];
#pragma unroll
            for (int r = 0; r < 4; ++r) {
                int i = i0 + wr * 32 + fi * 16 + lr * 4 + r;
                int j = j0 + wc * 32 + fj * 16 + lc;
                float w = 0.f;
                if (j < i) w = exp2f((float)(i - 1 - j) * L2D) * d[r];
                Wb[(size_t)i * TT + j] = (f16)w;
            }
        }
}

// ===== K5: aln = LN(W @ lnv), 16-row blocks (grid 16x8 = 128) ==============
__launch_bounds__(256)
__global__ void k_aln(const f16* __restrict__ Wf, const f16* __restrict__ lnvTf,
                      f16* __restrict__ alnf) {
    const int b = blockIdx.y;
    const int i0 = blockIdx.x * 16;
    const f16* A = Wf + (size_t)b * TT * TT;
    const f16* B = lnvTf + (size_t)b * DD * TT;
    const int t = threadIdx.x, lane = t & 63, w = t >> 6;
    const int lr = lane >> 4, lc = lane & 15;
    __shared__ __align__(16) f16 sA[2][16][40], sB[2][256][40];
    __shared__ float sS[4][16], sS2[4][16];
    const int arow = t >> 2, akq = (t & 3) * 8;
    f32x4 acc[4];
    const f32x4 z4 = {0.f, 0.f, 0.f, 0.f};
#pragma unroll
    for (int f = 0; f < 4; ++f) acc[f] = z4;

    const int NT = TT / 32;  // 8
    const f16* pa = A + (size_t)(i0 + arow) * TT + akq;
    const f16* pb = B + (size_t)arow * TT + akq;
    f16x8 va;
    f16x8 vb[4];
    if (t < 64) va = *(const f16x8*)pa;
#pragma unroll
    for (int q = 0; q < 4; ++q)
        vb[q] = *(const f16x8*)(pb + (size_t)q * 64 * TT);
    if (t < 64) *(f16x8*)&sA[0][arow][akq] = va;
#pragma unroll
    for (int q = 0; q < 4; ++q)
        *(f16x8*)&sB[0][q * 64 + arow][akq] = vb[q];
    __syncthreads();
    int cur = 0;
    for (int kt = 0; kt < NT; ++kt) {
        if (kt + 1 < NT) {
            int ko = (kt + 1) * 32;
            if (t < 64) va = *(const f16x8*)(pa + ko);
#pragma unroll
            for (int q = 0; q < 4; ++q)
                vb[q] = *(const f16x8*)(pb + (size_t)q * 64 * TT + ko);
        }
        f16x8 af = *(const f16x8*)&sA[cur][lc][lr * 8];
#pragma unroll
        for (int f = 0; f < 4; ++f) {
            f16x8 bf = *(const f16x8*)&sB[cur][w * 64 + f * 16 + lc][lr * 8];
            acc[f] = mfma16(af, bf, acc[f]);
        }
        if (kt + 1 < NT) {
            if (t < 64) *(f16x8*)&sA[cur ^ 1][arow][akq] = va;
#pragma unroll
            for (int q = 0; q < 4; ++q)
                *(f16x8*)&sB[cur ^ 1][q * 64 + arow][akq] = vb[q];
            __syncthreads();
            cur ^= 1;
        }
    }
    float s[4] = {}, s2[4] = {};
#pragma unroll
    for (int f = 0; f < 4; ++f)
#pragma unroll
        for (int r = 0; r < 4; ++r) { float v = acc[f][r]; s[r] += v; s2[r] += v * v; }
#pragma unroll
    for (int m = 1; m < 16; m <<= 1)
#pragma unroll
        for (int r = 0; r < 4; ++r) {
            s[r]  += __shfl_xor(s[r],  m, 64);
            s2[r] += __shfl_xor(s2[r], m, 64);
        }
    if (lc == 0)
#pragma unroll
        for (int r = 0; r < 4; ++r) { sS[w][lr * 4 + r] = s[r]; sS2[w][lr * 4 + r] = s2[r]; }
    __syncthreads();
    float mean[4], rstd[4];
#pragma unroll
    for (int r = 0; r < 4; ++r) {
        int row = lr * 4 + r;
        float tot  = sS[0][row] + sS[1][row] + sS[2][row] + sS[3][row];
        float tot2 = sS2[0][row] + sS2[1][row] + sS2[2][row] + sS2[3][row];
        mean[r] = tot * (1.f / 256.f);
        rstd[r] = rsqrtf(tot2 * (1.f / 256.f) - mean[r] * mean[r] + 1e-5f);
    }
#pragma unroll
    for (int f = 0; f < 4; ++f)
#pragma unroll
        for (int r = 0; r < 4; ++r) {
            int i = i0 + lr * 4 + r;
            int j = w * 64 + f * 16 + lc;
            alnf[((size_t)b * TT + i) * DD + j] = (f16)((acc[f][r] - mean[r]) * rstd[r]);
        }
}

// ===== K6: y = relu(aln @ Dy^T) * x, 64x128 tile, all f16 ==================
__launch_bounds__(256)
__global__ void k_y(const f16* __restrict__ A, const f16* __restrict__ B,
                    f16* __restrict__ yf, const f16* __restrict__ xf) {
    const int i0 = blockIdx.y * 64, j0 = blockIdx.x * 128;
    const int t = threadIdx.x, lane = t & 63, wid = t >> 6;
    const int wr = wid >> 1, wc = wid & 1;
    const int lr = lane >> 4, lc = lane & 15;
    __shared__ __align__(16) f16 sA[2][64][40], sB[2][128][40];
    const int arow = t >> 2, akq = (t & 3) * 8;
    f32x4 acc[2][4];
    const f32x4 z4 = {0.f, 0.f, 0.f, 0.f};
#pragma unroll
    for (int fi = 0; fi < 2; ++fi)
#pragma unroll
        for (int fj = 0; fj < 4; ++fj) acc[fi][fj] = z4;

    const int NT = DD / 32;  // 8
    const f16* pa  = A + (size_t)(i0 + arow) * DD + akq;
    const f16* pb0 = B + (size_t)(j0 + arow) * DD + akq;
    const f16* pb1 = B + (size_t)(j0 + 64 + arow) * DD + akq;
    f16x8 va  = *(const f16x8*)pa;
    f16x8 vb0 = *(const f16x8*)pb0;
    f16x8 vb1 = *(const f16x8*)pb1;
    *(f16x8*)&sA[0][arow][akq]      = va;
    *(f16x8*)&sB[0][arow][akq]      = vb0;
    *(f16x8*)&sB[0][64 + arow][akq] = vb1;
    __syncthreads();
    int cur = 0;
    for (int kt = 0; kt < NT; ++kt) {
        if (kt + 1 < NT) {
            int ko = (kt + 1) * 32;
            va  = *(const f16x8*)(pa + ko);
            vb0 = *(const f16x8*)(pb0 + ko);
            vb1 = *(const f16x8*)(pb1 + ko);
        }
        f16x8 ah[2], bh[4];
#pragma unroll
        for (int fi = 0; fi < 2; ++fi)
            ah[fi] = *(const f16x8*)&sA[cur][wr * 32 + fi * 16 + lc][lr * 8];
#pragma unroll
        for (int fj = 0; fj < 4; ++fj)
            bh[fj] = *(const f16x8*)&sB[cur][wc * 64 + fj * 16 + lc][lr * 8];
#pragma unroll
        for (int fi = 0; fi < 2; ++fi)
#pragma unroll
            for (int fj = 0; fj < 4; ++fj)
                acc[fi][fj] = mfma16(ah[fi], bh[fj], acc[fi][fj]);
        if (kt + 1 < NT) {
            *(f16x8*)&sA[cur ^ 1][arow][akq]      = va;
            *(f16x8*)&sB[cur ^ 1][arow][akq]      = vb0;
            *(f16x8*)&sB[cur ^ 1][64 + arow][akq] = vb1;
            __syncthreads();
            cur ^= 1;
        }
    }
#pragma unroll
    for (int fi = 0; fi < 2; ++fi)
#pragma unroll
        for (int fj = 0; fj < 4; ++fj) {
            f32x4 d = acc[fi][fj];
#pragma unroll
            for (int r = 0; r < 4; ++r) {
                int i = i0 + wr * 32 + fi * 16 + lr * 4 + r;
                int j = j0 + wc * 64 + fj * 16 + lc;
                size_t o = (size_t)i * NN + j;
                float vv = fmaxf(d[r], 0.f) * (float)xf[o];
                yf[o] = (f16)vv;
            }
        }
}

// ===== K7: vpart[z] = y @ E^T (K-half z), 64x64 tile, all f16 ==============
__launch_bounds__(256)
__global__ void k_vg(const f16* __restrict__ yf, const f16* __restrict__ Ef,
                     float* __restrict__ vpart) {
    const int z = blockIdx.z;
    float* C = vpart + (size_t)z * ROWS * DD;
    const int i0 = blockIdx.y * 64, j0 = blockIdx.x * 64;
    const int t = threadIdx.x, lane = t & 63, wid = t >> 6;
    const int wr = wid >> 1, wc = wid & 1;
    const int lr = lane >> 4, lc = lane & 15;
    __shared__ __align__(16) f16 sA[2][64][40], sB[2][64][40];
    const int srow = t >> 2, skq = (t & 3) * 8;
    f32x4 acc[2][2];
    const f32x4 z4 = {0.f, 0.f, 0.f, 0.f};
    acc[0][0] = z4; acc[0][1] = z4; acc[1][0] = z4; acc[1][1] = z4;

    const int NT = 512 / 32;  // 16
    const f16* pa = yf + (size_t)(i0 + srow) * NN + z * 512 + skq;
    const f16* pb = Ef + (size_t)(j0 + srow) * NN + z * 512 + skq;
    f16x8 va = *(const f16x8*)pa;
    f16x8 vb = *(const f16x8*)pb;
    *(f16x8*)&sA[0][srow][skq] = va;
    *(f16x8*)&sB[0][srow][skq] = vb;
    __syncthreads();
    int cur = 0;
    for (int kt = 0; kt < NT; ++kt) {
        if (kt + 1 < NT) {
            va = *(const f16x8*)(pa + (kt + 1) * 32);
            vb = *(const f16x8*)(pb + (kt + 1) * 32);
        }
        f16x8 ah0 = *(const f16x8*)&sA[cur][wr * 32 + lc][lr * 8];
        f16x8 ah1 = *(const f16x8*)&sA[cur][wr * 32 + 16 + lc][lr * 8];
        f16x8 bh0 = *(const f16x8*)&sB[cur][wc * 32 + lc][lr * 8];
        f16x8 bh1 = *(const f16x8*)&sB[cur][wc * 32 + 16 + lc][lr * 8];
        acc[0][0] = mfma16(ah0, bh0, acc[0][0]);
        acc[0][1] = mfma16(ah0, bh1, acc[0][1]);
        acc[1][0] = mfma16(ah1, bh0, acc[1][0]);
        acc[1][1] = mfma16(ah1, bh1, acc[1][1]);
        if (kt + 1 < NT) {
            *(f16x8*)&sA[cur ^ 1][srow][skq] = va;
            *(f16x8*)&sB[cur ^ 1][srow][skq] = vb;
            __syncthreads();
            cur ^= 1;
        }
    }
#pragma unroll
    for (int fi = 0; fi < 2; ++fi)
#pragma unroll
        for (int fj = 0; fj < 2; ++fj) {
            f32x4 d = acc[fi][fj];
#pragma unroll
            for (int r = 0; r < 4; ++r) {
                int i = i0 + wr * 32 + fi * 16 + lr * 4 + r;
                int j = j0 + wc * 32 + fj * 16 + lc;
                C[(size_t)i * DD + j] = d[r];
            }
        }
}

// ===== K8: out = LN(vpart0 + vpart1) ======================================
__launch_bounds__(256)
__global__ void ln2_kernel(const float* __restrict__ in, const float* __restrict__ in2,
                           float* __restrict__ outf) {
    int wave = threadIdx.x >> 6;
    int lane = threadIdx.x & 63;
    int row  = blockIdx.x * 4 + wave;
    float4 v = *(const float4*)(in + (size_t)row * DD + lane * 4);
    float4 w = *(const float4*)(in2 + (size_t)row * DD + lane * 4);
    v.x += w.x; v.y += w.y; v.z += w.z; v.w += w.w;
    float s  = v.x + v.y + v.z + v.w;
    float s2 = v.x*v.x + v.y*v.y + v.z*v.z + v.w*v.w;
#pragma unroll
    for (int o = 32; o; o >>= 1) {
        s  += __shfl_xor(s,  o, 64);
        s2 += __shfl_xor(s2, o, 64);
    }
    float m  = s * (1.0f / 256.0f);
    float sc = rsqrtf(s2 * (1.0f / 256.0f) - m * m + 1e-5f);
    float4 o4 = {(v.x - m) * sc, (v.y - m) * sc, (v.z - m) * sc, (v.w - m) * sc};
    *(float4*)(outf + (size_t)row * DD + lane * 4) = o4;
}

extern "C" void kernel_launch(void* const* d_in, const int* in_sizes, int n_in,
                              void* d_out, int out_size, void* d_ws, size_t ws_size,
                              hipStream_t stream) {
    (void)in_sizes; (void)n_in; (void)out_size; (void)ws_size;
    const float* emb = (const float*)d_in[0];   // (B,T,d)
    const float* E   = (const float*)d_in[1];   // (d,n)
    const float* Dx  = (const float*)d_in[2];   // (n,d)
    const float* Dy  = (const float*)d_in[3];   // (n,d)
    float* out = (float*)d_out;                 // (B,T,d)

    char* wsb = (char*)d_ws;
    f16*   embf  = (f16*)(wsb + 0);          // 1 MB
    f16*   Ef    = (f16*)(wsb + 1048576);    // 512 KB
    f16*   Dxf   = (f16*)(wsb + 1572864);    // 512 KB
    f16*   Dyf   = (f16*)(wsb + 2097152);    // 512 KB
    f16*   lnvTf = (f16*)(wsb + 2621440);    // 1 MB   [b][j][t]
    f16*   xuh   = (f16*)(wsb + 3670016);    // 4 MB
    f16*   xf    = (f16*)(wsb + 7864320);    // 4 MB
    f16*   Wf    = (f16*)(wsb + 12058624);   // 1 MB
    f16*   alnf  = (f16*)(wsb + 13107200);   // 1 MB
    f16*   yf    = (f16*)(wsb + 14155776);   // 4 MB
    float* vpart = (float*)(wsb + 18350080); // 4 MB (2 x ROWS*DD)
    float* Spart = (float*)(wsb + 22544384); // 64 KB (8 x ROWS)

    // K1: f16 conversions + LN^T(emb)
    cvtln_kernel<<<1280 + ROWS / 16, 256, 0, stream>>>(
        emb, E, Dx, Dy, embf, Ef, Dxf, Dyf, lnvTf);
    // K2: xu = relu(emb @ Dx^T) -> f16 + row-sum partials
    k_xu<<<dim3(NN / 128, ROWS / 64), 256, 0, stream>>>(embf, Dxf, xuh, Spart);
    // K3: x scan (coalesced 8x32 mapping)
    k_xscan<<<BB * 32, 256, 0, stream>>>(xuh, Spart, xf);
    // K4: W = mask . (X X^T)
    k_W<<<dim3(TT / 64, TT / 64, BB), 256, 0, stream>>>(xf, Wf);
    // K5: aln = LN(W @ lnv), 16-row blocks
    k_aln<<<dim3(TT / 16, BB), 256, 0, stream>>>(Wf, lnvTf, alnf);
    // K6: y = relu(aln @ Dy^T) * x
    k_y<<<dim3(NN / 128, ROWS / 64), 256, 0, stream>>>(alnf, Dyf, yf, xf);
    // K7: vpart = y @ E^T split-K=2
    k_vg<<<dim3(DD / 64, ROWS / 64, 2), 256, 0, stream>>>(yf, Ef, vpart);
    // K8: out = LN(vpart0 + vpart1)
    ln2_kernel<<<ROWS / 4, 256, 0, stream>>>(
        vpart, vpart + (size_t)ROWS * DD, out);
}

// Round 17
// 56.020 us; speedup vs baseline: 1.5827x; 1.0329x over previous
//
#include <hip/hip_runtime.h>
#include <math.h>

// BDH recurrence, 8-kernel pipeline (round-16 base, 57.9us) with BK=64
// double-buffered staging in the two long-K GEMMs (k_W, k_vg) to halve
// per-K-step latency exposure. fp16 MFMA GEMMs (f32 accum).
//  K1 cvt(emb,E,Dx,Dy)->f16 + LN^T(emb)->f16                      1408
//  K2 xu = relu(emb @ Dx^T) -> f16 + rowsum partials              (8,32)
//  K3 x-scan (8 chunks x 32 j, 64B segments)                      256
//  K4 W = causal-decay mask . (X X^T)  batched, BK=64             (4,4,8)
//  K5 aln = LN(W @ lnv), 16-row blocks (grid 128)                 (16,8)
//  K6 y = relu(aln @ Dy^T) * x                                    (8,32)
//  K7 vpart = y @ E^T  split-K=2, BK=64                           (4,32,2)
//  K8 out = LN(vpart0+vpart1)                                     512

#define TT 256
#define BB 8
#define DD 256
#define NN 1024
#define ROWS (BB*TT)   // 2048

using f16   = _Float16;
using f16x4 = __attribute__((ext_vector_type(4))) _Float16;
using f16x8 = __attribute__((ext_vector_type(8))) _Float16;
using f32x4 = __attribute__((ext_vector_type(4))) float;

__device__ inline f32x4 mfma16(f16x8 a, f16x8 b, f32x4 c) {
    return __builtin_amdgcn_mfma_f32_16x16x32_f16(a, b, c, 0, 0, 0);
}

// ===== K1: convert inputs to fp16 + LN-transpose of emb ====================
__launch_bounds__(256)
__global__ void cvtln_kernel(const float* __restrict__ emb, const float* __restrict__ E,
                             const float* __restrict__ Dx, const float* __restrict__ Dy,
                             f16* __restrict__ embf, f16* __restrict__ Ef,
                             f16* __restrict__ Dxf, f16* __restrict__ Dyf,
                             f16* __restrict__ lnvTf) {
    __shared__ f16 sT[256][24];
    if (blockIdx.x < 1280) {
        int base = (blockIdx.x * 256 + threadIdx.x) * 4;
        const float* s; f16* d; int loc;
        if      (base <  524288) { s = emb; d = embf; loc = base; }
        else if (base <  786432) { s = E;   d = Ef;   loc = base - 524288; }
        else if (base < 1048576) { s = Dx;  d = Dxf;  loc = base - 786432; }
        else                     { s = Dy;  d = Dyf;  loc = base - 1048576; }
        float4 v = *(const float4*)(s + loc);
        f16x4 h = {(f16)v.x, (f16)v.y, (f16)v.z, (f16)v.w};
        *(f16x4*)(d + loc) = h;
        return;
    }
    const int bx = blockIdx.x - 1280;
    const int b  = bx >> 4;
    const int t0 = (bx & 15) * 16;
    const int wave = threadIdx.x >> 6;
    const int lane = threadIdx.x & 63;
#pragma unroll
    for (int rr = 0; rr < 4; ++rr) {
        int tloc = wave * 4 + rr;
        const float* p = emb + ((size_t)b * TT + t0 + tloc) * DD;
        float4 v = *(const float4*)(p + lane * 4);
        float s  = v.x + v.y + v.z + v.w;
        float s2 = v.x*v.x + v.y*v.y + v.z*v.z + v.w*v.w;
#pragma unroll
        for (int o = 32; o; o >>= 1) {
            s  += __shfl_xor(s,  o, 64);
            s2 += __shfl_xor(s2, o, 64);
        }
        float m   = s * (1.0f / 256.0f);
        float sc  = rsqrtf(s2 * (1.0f / 256.0f) - m * m + 1e-5f);
        sT[lane * 4 + 0][tloc] = (f16)((v.x - m) * sc);
        sT[lane * 4 + 1][tloc] = (f16)((v.y - m) * sc);
        sT[lane * 4 + 2][tloc] = (f16)((v.z - m) * sc);
        sT[lane * 4 + 3][tloc] = (f16)((v.w - m) * sc);
    }
    __syncthreads();
    int j = threadIdx.x;
    size_t o = ((size_t)b * DD + j) * TT + t0;
    *(f16x8*)(lnvTf + o)     = *(const f16x8*)&sT[j][0];
    *(f16x8*)(lnvTf + o + 8) = *(const f16x8*)&sT[j][8];
}

// ===== K2: xu = relu(emb @ Dx^T) -> f16, 64x128 tile, + Spart ==============
__launch_bounds__(256)
__global__ void k_xu(const f16* __restrict__ A, const f16* __restrict__ B,
                     f16* __restrict__ xuh, float* __restrict__ Spart) {
    const int i0 = blockIdx.y * 64, j0 = blockIdx.x * 128;
    const int t = threadIdx.x, lane = t & 63, wid = t >> 6;
    const int wr = wid >> 1, wc = wid & 1;
    const int lr = lane >> 4, lc = lane & 15;
    __shared__ __align__(16) f16 sA[2][64][40], sB[2][128][40];
    __shared__ float ssum[64][2];
    const int arow = t >> 2, akq = (t & 3) * 8;
    f32x4 acc[2][4];
    const f32x4 z4 = {0.f, 0.f, 0.f, 0.f};
#pragma unroll
    for (int fi = 0; fi < 2; ++fi)
#pragma unroll
        for (int fj = 0; fj < 4; ++fj) acc[fi][fj] = z4;

    const int NT = DD / 32;  // 8
    const f16* pa  = A + (size_t)(i0 + arow) * DD + akq;
    const f16* pb0 = B + (size_t)(j0 + arow) * DD + akq;
    const f16* pb1 = B + (size_t)(j0 + 64 + arow) * DD + akq;
    f16x8 va  = *(const f16x8*)pa;
    f16x8 vb0 = *(const f16x8*)pb0;
    f16x8 vb1 = *(const f16x8*)pb1;
    *(f16x8*)&sA[0][arow][akq]      = va;
    *(f16x8*)&sB[0][arow][akq]      = vb0;
    *(f16x8*)&sB[0][64 + arow][akq] = vb1;
    __syncthreads();
    int cur = 0;
    for (int kt = 0; kt < NT; ++kt) {
        if (kt + 1 < NT) {
            int ko = (kt + 1) * 32;
            va  = *(const f16x8*)(pa + ko);
            vb0 = *(const f16x8*)(pb0 + ko);
            vb1 = *(const f16x8*)(pb1 + ko);
        }
        f16x8 ah[2], bh[4];
#pragma unroll
        for (int fi = 0; fi < 2; ++fi)
            ah[fi] = *(const f16x8*)&sA[cur][wr * 32 + fi * 16 + lc][lr * 8];
#pragma unroll
        for (int fj = 0; fj < 4; ++fj)
            bh[fj] = *(const f16x8*)&sB[cur][wc * 64 + fj * 16 + lc][lr * 8];
#pragma unroll
        for (int fi = 0; fi < 2; ++fi)
#pragma unroll
            for (int fj = 0; fj < 4; ++fj)
                acc[fi][fj] = mfma16(ah[fi], bh[fj], acc[fi][fj]);
        if (kt + 1 < NT) {
            *(f16x8*)&sA[cur ^ 1][arow][akq]      = va;
            *(f16x8*)&sB[cur ^ 1][arow][akq]      = vb0;
            *(f16x8*)&sB[cur ^ 1][64 + arow][akq] = vb1;
            __syncthreads();
            cur ^= 1;
        }
    }
    float rs[2][4] = {};
#pragma unroll
    for (int fi = 0; fi < 2; ++fi)
#pragma unroll
        for (int fj = 0; fj < 4; ++fj) {
            f32x4 d = acc[fi][fj];
#pragma unroll
            for (int r = 0; r < 4; ++r) {
                int i = i0 + wr * 32 + fi * 16 + lr * 4 + r;
                int j = j0 + wc * 64 + fj * 16 + lc;
                float vv = fmaxf(d[r], 0.f);
                xuh[(size_t)i * NN + j] = (f16)vv;
                rs[fi][r] += vv;
            }
        }
#pragma unroll
    for (int fi = 0; fi < 2; ++fi)
#pragma unroll
        for (int r = 0; r < 4; ++r) {
            float v = rs[fi][r];
#pragma unroll
            for (int m = 1; m < 16; m <<= 1) v += __shfl_xor(v, m, 64);
            if (lc == 0) ssum[wr * 32 + fi * 16 + lr * 4 + r][wc] = v;
        }
    __syncthreads();
    if (t < 64) Spart[(size_t)blockIdx.x * ROWS + i0 + t] = ssum[t][0] + ssum[t][1];
}

// ===== K3: x-scan, 8 chunks x 32 j (64B segments), inline normalizer =======
__launch_bounds__(256)
__global__ void k_xscan(const f16* __restrict__ xuh, const float* __restrict__ Spart,
                        f16* __restrict__ xf) {
    __shared__ float Gs[8][33], Hs[8][33], Cs[8][33];
    __shared__ float sS[256], sRC[256];
    __shared__ int bad;
    const int b = blockIdx.x >> 5, jgrp = blockIdx.x & 31;
    const int tid = threadIdx.x;
    float s = 0.f;
#pragma unroll
    for (int g = 0; g < 8; ++g) s += Spart[(size_t)g * ROWS + b * TT + tid];
    if (tid == 0) bad = 0;
    sS[tid] = s;
    __syncthreads();
    float us = (tid == 0) ? s : (0.97f + s);
    if (us < 1e-12f) bad = 1;
    __syncthreads();
    if (!bad) {
        sRC[tid] = 1.0f / us;
    } else if (tid == 0) {
        float sigma = 0.f;
        for (int tt = 0; tt < TT; ++tt) {
            float u2 = fmaf(0.97f, sigma, sS[tt]);
            float r  = 1.0f / fmaxf(u2, 1e-12f);
            sRC[tt] = r;
            sigma = u2 * r;
        }
    }
    __syncthreads();

    const int ck = tid >> 5, jl = tid & 31;
    const int j  = jgrp * 32 + jl;
    const size_t base = ((size_t)b * TT + ck * 32) * NN + j;
    float xur[32], rcr[32];
#pragma unroll
    for (int i = 0; i < 32; ++i) xur[i] = (float)xuh[base + (size_t)i * NN];
#pragma unroll
    for (int i = 0; i < 32; ++i) rcr[i] = sRC[ck * 32 + i];
    float xs = 0.f, G = 1.f;
#pragma unroll
    for (int i = 0; i < 32; ++i) {
        xs = fmaf(0.97f, xs, xur[i]) * rcr[i];
        G *= 0.97f * rcr[i];
    }
    Gs[ck][jl] = G;
    Hs[ck][jl] = xs;
    __syncthreads();
    if (tid < 32) {
        float cr = 0.f;
        Cs[0][tid] = 0.f;
#pragma unroll
        for (int cc = 0; cc < 7; ++cc) {
            cr = fmaf(Gs[cc][tid], cr, Hs[cc][tid]);
            Cs[cc + 1][tid] = cr;
        }
    }
    __syncthreads();
    xs = Cs[ck][jl];
#pragma unroll
    for (int i = 0; i < 32; ++i) {
        xs = fmaf(0.97f, xs, xur[i]) * rcr[i];
        xf[base + (size_t)i * NN] = (f16)xs;
    }
}

// ===== K4: W = causal-decay mask . (X X^T), 64x64, batched, BK=64 ==========
__launch_bounds__(256)
__global__ void k_W(const f16* __restrict__ xf, f16* __restrict__ Wf) {
    const int b = blockIdx.z;
    const f16* X = xf + (size_t)b * TT * NN;
    f16* Wb = Wf + (size_t)b * TT * TT;
    const int i0 = blockIdx.y * 64, j0 = blockIdx.x * 64;
    const int t = threadIdx.x, lane = t & 63, wid = t >> 6;
    const int wr = wid >> 1, wc = wid & 1;
    const int lr = lane >> 4, lc = lane & 15;
    const float L2D = -0.043943348f;  // log2(0.97)

    if (j0 > i0) {
#pragma unroll
        for (int fi = 0; fi < 2; ++fi)
#pragma unroll
            for (int fj = 0; fj < 2; ++fj)
#pragma unroll
                for (int r = 0; r < 4; ++r) {
                    int i = i0 + wr * 32 + fi * 16 + lr * 4 + r;
                    int j = j0 + wc * 32 + fj * 16 + lc;
                    Wb[(size_t)i * TT + j] = (f16)0.f;
                }
        return;
    }

    __shared__ __align__(16) f16 sA[2][64][72], sB[2][64][72];
    const int srow = t >> 2, skq = (t & 3) * 16;
    f32x4 acc[2][2];
    const f32x4 z4 = {0.f, 0.f, 0.f, 0.f};
    acc[0][0] = z4; acc[0][1] = z4; acc[1][0] = z4; acc[1][1] = z4;

    const int NT = NN / 64;  // 16
    const f16* pa = X + (size_t)(i0 + srow) * NN + skq;
    const f16* pb = X + (size_t)(j0 + srow) * NN + skq;
    f16x8 va0 = *(const f16x8*)pa,       va1 = *(const f16x8*)(pa + 8);
    f16x8 vb0 = *(const f16x8*)pb,       vb1 = *(const f16x8*)(pb + 8);
    *(f16x8*)&sA[0][srow][skq]     = va0;
    *(f16x8*)&sA[0][srow][skq + 8] = va1;
    *(f16x8*)&sB[0][srow][skq]     = vb0;
    *(f16x8*)&sB[0][srow][skq + 8] = vb1;
    __syncthreads();
    int cur = 0;
    for (int kt = 0; kt < NT; ++kt) {
        if (kt + 1 < NT) {
            int ko = (kt + 1) * 64;
            va0 = *(const f16x8*)(pa + ko);  va1 = *(const f16x8*)(pa + ko + 8);
            vb0 = *(const f16x8*)(pb + ko);  vb1 = *(const f16x8*)(pb + ko + 8);
        }
#pragma unroll
        for (int ks = 0; ks < 2; ++ks) {
            f16x8 ah0 = *(const f16x8*)&sA[cur][wr * 32 + lc][ks * 32 + lr * 8];
            f16x8 ah1 = *(const f16x8*)&sA[cur][wr * 32 + 16 + lc][ks * 32 + lr * 8];
            f16x8 bh0 = *(const f16x8*)&sB[cur][wc * 32 + lc][ks * 32 + lr * 8];
            f16x8 bh1 = *(const f16x8*)&sB[cur][wc * 32 + 16 + lc][ks * 32 + lr * 8];
            acc[0][0] = mfma16(ah0, bh0, acc[0][0]);
            acc[0][1] = mfma16(ah0, bh1, acc[0][1]);
            acc[1][0] = mfma16(ah1, bh0, acc[1][0]);
            acc[1][1] = mfma16(ah1, bh1, acc[1][1]);
        }
        if (kt + 1 < NT) {
            *(f16x8*)&sA[cur ^ 1][srow][skq]     = va0;
            *(f16x8*)&sA[cur ^ 1][srow][skq + 8] = va1;
            *(f16x8*)&sB[cur ^ 1][srow][skq]     = vb0;
            *(f16x8*)&sB[cur ^ 1][srow][skq + 8] = vb1;
            __syncthreads();
            cur ^= 1;
        }
    }
#pragma unroll
    for (int fi = 0; fi < 2; ++fi)
#pragma unroll
        for (int fj = 0; fj < 2; ++fj) {
            f32x4 d = acc[fi][fj];
#pragma unroll
            for (int r = 0; r < 4; ++r) {
                int i = i0 + wr * 32 + fi * 16 + lr * 4 + r;
                int j = j0 + wc * 32 + fj * 16 + lc;
                float w = 0.f;
                if (j < i) w = exp2f((float)(i - 1 - j) * L2D) * d[r];
                Wb[(size_t)i * TT + j] = (f16)w;
            }
        }
}

// ===== K5: aln = LN(W @ lnv), 16-row blocks (grid 16x8 = 128) ==============
__launch_bounds__(256)
__global__ void k_aln(const f16* __restrict__ Wf, const f16* __restrict__ lnvTf,
                      f16* __restrict__ alnf) {
    const int b = blockIdx.y;
    const int i0 = blockIdx.x * 16;
    const f16* A = Wf + (size_t)b * TT * TT;
    const f16* B = lnvTf + (size_t)b * DD * TT;
    const int t = threadIdx.x, lane = t & 63, w = t >> 6;
    const int lr = lane >> 4, lc = lane & 15;
    __shared__ __align__(16) f16 sA[2][16][40], sB[2][256][40];
    __shared__ float sS[4][16], sS2[4][16];
    const int arow = t >> 2, akq = (t & 3) * 8;
    f32x4 acc[4];
    const f32x4 z4 = {0.f, 0.f, 0.f, 0.f};
#pragma unroll
    for (int f = 0; f < 4; ++f) acc[f] = z4;

    const int NT = TT / 32;  // 8
    const f16* pa = A + (size_t)(i0 + arow) * TT + akq;
    const f16* pb = B + (size_t)arow * TT + akq;
    f16x8 va;
    f16x8 vb[4];
    if (t < 64) va = *(const f16x8*)pa;
#pragma unroll
    for (int q = 0; q < 4; ++q)
        vb[q] = *(const f16x8*)(pb + (size_t)q * 64 * TT);
    if (t < 64) *(f16x8*)&sA[0][arow][akq] = va;
#pragma unroll
    for (int q = 0; q < 4; ++q)
        *(f16x8*)&sB[0][q * 64 + arow][akq] = vb[q];
    __syncthreads();
    int cur = 0;
    for (int kt = 0; kt < NT; ++kt) {
        if (kt + 1 < NT) {
            int ko = (kt + 1) * 32;
            if (t < 64) va = *(const f16x8*)(pa + ko);
#pragma unroll
            for (int q = 0; q < 4; ++q)
                vb[q] = *(const f16x8*)(pb + (size_t)q * 64 * TT + ko);
        }
        f16x8 af = *(const f16x8*)&sA[cur][lc][lr * 8];
#pragma unroll
        for (int f = 0; f < 4; ++f) {
            f16x8 bf = *(const f16x8*)&sB[cur][w * 64 + f * 16 + lc][lr * 8];
            acc[f] = mfma16(af, bf, acc[f]);
        }
        if (kt + 1 < NT) {
            if (t < 64) *(f16x8*)&sA[cur ^ 1][arow][akq] = va;
#pragma unroll
            for (int q = 0; q < 4; ++q)
                *(f16x8*)&sB[cur ^ 1][q * 64 + arow][akq] = vb[q];
            __syncthreads();
            cur ^= 1;
        }
    }
    float s[4] = {}, s2[4] = {};
#pragma unroll
    for (int f = 0; f < 4; ++f)
#pragma unroll
        for (int r = 0; r < 4; ++r) { float v = acc[f][r]; s[r] += v; s2[r] += v * v; }
#pragma unroll
    for (int m = 1; m < 16; m <<= 1)
#pragma unroll
        for (int r = 0; r < 4; ++r) {
            s[r]  += __shfl_xor(s[r],  m, 64);
            s2[r] += __shfl_xor(s2[r], m, 64);
        }
    if (lc == 0)
#pragma unroll
        for (int r = 0; r < 4; ++r) { sS[w][lr * 4 + r] = s[r]; sS2[w][lr * 4 + r] = s2[r]; }
    __syncthreads();
    float mean[4], rstd[4];
#pragma unroll
    for (int r = 0; r < 4; ++r) {
        int row = lr * 4 + r;
        float tot  = sS[0][row] + sS[1][row] + sS[2][row] + sS[3][row];
        float tot2 = sS2[0][row] + sS2[1][row] + sS2[2][row] + sS2[3][row];
        mean[r] = tot * (1.f / 256.f);
        rstd[r] = rsqrtf(tot2 * (1.f / 256.f) - mean[r] * mean[r] + 1e-5f);
    }
#pragma unroll
    for (int f = 0; f < 4; ++f)
#pragma unroll
        for (int r = 0; r < 4; ++r) {
            int i = i0 + lr * 4 + r;
            int j = w * 64 + f * 16 + lc;
            alnf[((size_t)b * TT + i) * DD + j] = (f16)((acc[f][r] - mean[r]) * rstd[r]);
        }
}

// ===== K6: y = relu(aln @ Dy^T) * x, 64x128 tile, all f16 ==================
__launch_bounds__(256)
__global__ void k_y(const f16* __restrict__ A, const f16* __restrict__ B,
                    f16* __restrict__ yf, const f16* __restrict__ xf) {
    const int i0 = blockIdx.y * 64, j0 = blockIdx.x * 128;
    const int t = threadIdx.x, lane = t & 63, wid = t >> 6;
    const int wr = wid >> 1, wc = wid & 1;
    const int lr = lane >> 4, lc = lane & 15;
    __shared__ __align__(16) f16 sA[2][64][40], sB[2][128][40];
    const int arow = t >> 2, akq = (t & 3) * 8;
    f32x4 acc[2][4];
    const f32x4 z4 = {0.f, 0.f, 0.f, 0.f};
#pragma unroll
    for (int fi = 0; fi < 2; ++fi)
#pragma unroll
        for (int fj = 0; fj < 4; ++fj) acc[fi][fj] = z4;

    const int NT = DD / 32;  // 8
    const f16* pa  = A + (size_t)(i0 + arow) * DD + akq;
    const f16* pb0 = B + (size_t)(j0 + arow) * DD + akq;
    const f16* pb1 = B + (size_t)(j0 + 64 + arow) * DD + akq;
    f16x8 va  = *(const f16x8*)pa;
    f16x8 vb0 = *(const f16x8*)pb0;
    f16x8 vb1 = *(const f16x8*)pb1;
    *(f16x8*)&sA[0][arow][akq]      = va;
    *(f16x8*)&sB[0][arow][akq]      = vb0;
    *(f16x8*)&sB[0][64 + arow][akq] = vb1;
    __syncthreads();
    int cur = 0;
    for (int kt = 0; kt < NT; ++kt) {
        if (kt + 1 < NT) {
            int ko = (kt + 1) * 32;
            va  = *(const f16x8*)(pa + ko);
            vb0 = *(const f16x8*)(pb0 + ko);
            vb1 = *(const f16x8*)(pb1 + ko);
        }
        f16x8 ah[2], bh[4];
#pragma unroll
        for (int fi = 0; fi < 2; ++fi)
            ah[fi] = *(const f16x8*)&sA[cur][wr * 32 + fi * 16 + lc][lr * 8];
#pragma unroll
        for (int fj = 0; fj < 4; ++fj)
            bh[fj] = *(const f16x8*)&sB[cur][wc * 64 + fj * 16 + lc][lr * 8];
#pragma unroll
        for (int fi = 0; fi < 2; ++fi)
#pragma unroll
            for (int fj = 0; fj < 4; ++fj)
                acc[fi][fj] = mfma16(ah[fi], bh[fj], acc[fi][fj]);
        if (kt + 1 < NT) {
            *(f16x8*)&sA[cur ^ 1][arow][akq]      = va;
            *(f16x8*)&sB[cur ^ 1][arow][akq]      = vb0;
            *(f16x8*)&sB[cur ^ 1][64 + arow][akq] = vb1;
            __syncthreads();
            cur ^= 1;
        }
    }
#pragma unroll
    for (int fi = 0; fi < 2; ++fi)
#pragma unroll
        for (int fj = 0; fj < 4; ++fj) {
            f32x4 d = acc[fi][fj];
#pragma unroll
            for (int r = 0; r < 4; ++r) {
                int i = i0 + wr * 32 + fi * 16 + lr * 4 + r;
                int j = j0 + wc * 64 + fj * 16 + lc;
                size_t o = (size_t)i * NN + j;
                float vv = fmaxf(d[r], 0.f) * (float)xf[o];
                yf[o] = (f16)vv;
            }
        }
}

// ===== K7: vpart[z] = y @ E^T (K-half z), 64x64 tile, BK=64 ================
__launch_bounds__(256)
__global__ void k_vg(const f16* __restrict__ yf, const f16* __restrict__ Ef,
                     float* __restrict__ vpart) {
    const int z = blockIdx.z;
    float* C = vpart + (size_t)z * ROWS * DD;
    const int i0 = blockIdx.y * 64, j0 = blockIdx.x * 64;
    const int t = threadIdx.x, lane = t & 63, wid = t >> 6;
    const int wr = wid >> 1, wc = wid & 1;
    const int lr = lane >> 4, lc = lane & 15;
    __shared__ __align__(16) f16 sA[2][64][72], sB[2][64][72];
    const int srow = t >> 2, skq = (t & 3) * 16;
    f32x4 acc[2][2];
    const f32x4 z4 = {0.f, 0.f, 0.f, 0.f};
    acc[0][0] = z4; acc[0][1] = z4; acc[1][0] = z4; acc[1][1] = z4;

    const int NT = 512 / 64;  // 8
    const f16* pa = yf + (size_t)(i0 + srow) * NN + z * 512 + skq;
    const f16* pb = Ef + (size_t)(j0 + srow) * NN + z * 512 + skq;
    f16x8 va0 = *(const f16x8*)pa,       va1 = *(const f16x8*)(pa + 8);
    f16x8 vb0 = *(const f16x8*)pb,       vb1 = *(const f16x8*)(pb + 8);
    *(f16x8*)&sA[0][srow][skq]     = va0;
    *(f16x8*)&sA[0][srow][skq + 8] = va1;
    *(f16x8*)&sB[0][srow][skq]     = vb0;
    *(f16x8*)&sB[0][srow][skq + 8] = vb1;
    __syncthreads();
    int cur = 0;
    for (int kt = 0; kt < NT; ++kt) {
        if (kt + 1 < NT) {
            int ko = (kt + 1) * 64;
            va0 = *(const f16x8*)(pa + ko);  va1 = *(const f16x8*)(pa + ko + 8);
            vb0 = *(const f16x8*)(pb + ko);  vb1 = *(const f16x8*)(pb + ko + 8);
        }
#pragma unroll
        for (int ks = 0; ks < 2; ++ks) {
            f16x8 ah0 = *(const f16x8*)&sA[cur][wr * 32 + lc][ks * 32 + lr * 8];
            f16x8 ah1 = *(const f16x8*)&sA[cur][wr * 32 + 16 + lc][ks * 32 + lr * 8];
            f16x8 bh0 = *(const f16x8*)&sB[cur][wc * 32 + lc][ks * 32 + lr * 8];
            f16x8 bh1 = *(const f16x8*)&sB[cur][wc * 32 + 16 + lc][ks * 32 + lr * 8];
            acc[0][0] = mfma16(ah0, bh0, acc[0][0]);
            acc[0][1] = mfma16(ah0, bh1, acc[0][1]);
            acc[1][0] = mfma16(ah1, bh0, acc[1][0]);
            acc[1][1] = mfma16(ah1, bh1, acc[1][1]);
        }
        if (kt + 1 < NT) {
            *(f16x8*)&sA[cur ^ 1][srow][skq]     = va0;
            *(f16x8*)&sA[cur ^ 1][srow][skq + 8] = va1;
            *(f16x8*)&sB[cur ^ 1][srow][skq]     = vb0;
            *(f16x8*)&sB[cur ^ 1][srow][skq + 8] = vb1;
            __syncthreads();
            cur ^= 1;
        }
    }
#pragma unroll
    for (int fi = 0; fi < 2; ++fi)
#pragma unroll
        for (int fj = 0; fj < 2; ++fj) {
            f32x4 d = acc[fi][fj];
#pragma unroll
            for (int r = 0; r < 4; ++r) {
                int i = i0 + wr * 32 + fi * 16 + lr * 4 + r;
                int j = j0 + wc * 32 + fj * 16 + lc;
                C[(size_t)i * DD + j] = d[r];
            }
        }
}

// ===== K8: out = LN(vpart0 + vpart1) ======================================
__launch_bounds__(256)
__global__ void ln2_kernel(const float* __restrict__ in, const float* __restrict__ in2,
                           float* __restrict__ outf) {
    int wave = threadIdx.x >> 6;
    int lane = threadIdx.x & 63;
    int row  = blockIdx.x * 4 + wave;
    float4 v = *(const float4*)(in + (size_t)row * DD + lane * 4);
    float4 w = *(const float4*)(in2 + (size_t)row * DD + lane * 4);
    v.x += w.x; v.y += w.y; v.z += w.z; v.w += w.w;
    float s  = v.x + v.y + v.z + v.w;
    float s2 = v.x*v.x + v.y*v.y + v.z*v.z + v.w*v.w;
#pragma unroll
    for (int o = 32; o; o >>= 1) {
        s  += __shfl_xor(s,  o, 64);
        s2 += __shfl_xor(s2, o, 64);
    }
    float m  = s * (1.0f / 256.0f);
    float sc = rsqrtf(s2 * (1.0f / 256.0f) - m * m + 1e-5f);
    float4 o4 = {(v.x - m) * sc, (v.y - m) * sc, (v.z - m) * sc, (v.w - m) * sc};
    *(float4*)(outf + (size_t)row * DD + lane * 4) = o4;
}

extern "C" void kernel_launch(void* const* d_in, const int* in_sizes, int n_in,
                              void* d_out, int out_size, void* d_ws, size_t ws_size,
                              hipStream_t stream) {
    (void)in_sizes; (void)n_in; (void)out_size; (void)ws_size;
    const float* emb = (const float*)d_in[0];   // (B,T,d)
    const float* E   = (const float*)d_in[1];   // (d,n)
    const float* Dx  = (const float*)d_in[2];   // (n,d)
    const float* Dy  = (const float*)d_in[3];   // (n,d)
    float* out = (float*)d_out;                 // (B,T,d)

    char* wsb = (char*)d_ws;
    f16*   embf  = (f16*)(wsb + 0);          // 1 MB
    f16*   Ef    = (f16*)(wsb + 1048576);    // 512 KB
    f16*   Dxf   = (f16*)(wsb + 1572864);    // 512 KB
    f16*   Dyf   = (f16*)(wsb + 2097152);    // 512 KB
    f16*   lnvTf = (f16*)(wsb + 2621440);    // 1 MB   [b][j][t]
    f16*   xuh   = (f16*)(wsb + 3670016);    // 4 MB
    f16*   xf    = (f16*)(wsb + 7864320);    // 4 MB
    f16*   Wf    = (f16*)(wsb + 12058624);   // 1 MB
    f16*   alnf  = (f16*)(wsb + 13107200);   // 1 MB
    f16*   yf    = (f16*)(wsb + 14155776);   // 4 MB
    float* vpart = (float*)(wsb + 18350080); // 4 MB (2 x ROWS*DD)
    float* Spart = (float*)(wsb + 22544384); // 64 KB (8 x ROWS)

    // K1: f16 conversions + LN^T(emb)
    cvtln_kernel<<<1280 + ROWS / 16, 256, 0, stream>>>(
        emb, E, Dx, Dy, embf, Ef, Dxf, Dyf, lnvTf);
    // K2: xu = relu(emb @ Dx^T) -> f16 + row-sum partials
    k_xu<<<dim3(NN / 128, ROWS / 64), 256, 0, stream>>>(embf, Dxf, xuh, Spart);
    // K3: x scan (coalesced 8x32 mapping)
    k_xscan<<<BB * 32, 256, 0, stream>>>(xuh, Spart, xf);
    // K4: W = mask . (X X^T), BK=64
    k_W<<<dim3(TT / 64, TT / 64, BB), 256, 0, stream>>>(xf, Wf);
    // K5: aln = LN(W @ lnv), 16-row blocks
    k_aln<<<dim3(TT / 16, BB), 256, 0, stream>>>(Wf, lnvTf, alnf);
    // K6: y = relu(aln @ Dy^T) * x
    k_y<<<dim3(NN / 128, ROWS / 64), 256, 0, stream>>>(alnf, Dyf, yf, xf);
    // K7: vpart = y @ E^T split-K=2, BK=64
    k_vg<<<dim3(DD / 64, ROWS / 64, 2), 256, 0, stream>>>(yf, Ef, vpart);
    // K8: out = LN(vpart0 + vpart1)
    ln2_kernel<<<ROWS / 4, 256, 0, stream>>>(
        vpart, vpart + (size_t)ROWS * DD, out);
}

// Round 18
// 55.337 us; speedup vs baseline: 1.6022x; 1.0123x over previous
//
#include <hip/hip_runtime.h>
#include <math.h>

// BDH recurrence, 8-kernel pipeline (round-17 base, 56.0us) with BK=64
// staging extended to k_xu and k_y (K=256: 8 -> 4 steps). fp16 MFMA, f32 acc.
//  K1 cvt(emb,E,Dx,Dy)->f16 + LN^T(emb)->f16                      1408
//  K2 xu = relu(emb @ Dx^T) -> f16 + rowsum partials, BK=64       (8,32)
//  K3 x-scan (8 chunks x 32 j, 64B segments)                      256
//  K4 W = causal-decay mask . (X X^T)  batched, BK=64             (4,4,8)
//  K5 aln = LN(W @ lnv), 16-row blocks (grid 128)                 (16,8)
//  K6 y = relu(aln @ Dy^T) * x, BK=64                             (8,32)
//  K7 vpart = y @ E^T  split-K=2, BK=64                           (4,32,2)
//  K8 out = LN(vpart0+vpart1)                                     512

#define TT 256
#define BB 8
#define DD 256
#define NN 1024
#define ROWS (BB*TT)   // 2048

using f16   = _Float16;
using f16x4 = __attribute__((ext_vector_type(4))) _Float16;
using f16x8 = __attribute__((ext_vector_type(8))) _Float16;
using f32x4 = __attribute__((ext_vector_type(4))) float;

__device__ inline f32x4 mfma16(f16x8 a, f16x8 b, f32x4 c) {
    return __builtin_amdgcn_mfma_f32_16x16x32_f16(a, b, c, 0, 0, 0);
}

// ===== K1: convert inputs to fp16 + LN-transpose of emb ====================
__launch_bounds__(256)
__global__ void cvtln_kernel(const float* __restrict__ emb, const float* __restrict__ E,
                             const float* __restrict__ Dx, const float* __restrict__ Dy,
                             f16* __restrict__ embf, f16* __restrict__ Ef,
                             f16* __restrict__ Dxf, f16* __restrict__ Dyf,
                             f16* __restrict__ lnvTf) {
    __shared__ f16 sT[256][24];
    if (blockIdx.x < 1280) {
        int base = (blockIdx.x * 256 + threadIdx.x) * 4;
        const float* s; f16* d; int loc;
        if      (base <  524288) { s = emb; d = embf; loc = base; }
        else if (base <  786432) { s = E;   d = Ef;   loc = base - 524288; }
        else if (base < 1048576) { s = Dx;  d = Dxf;  loc = base - 786432; }
        else                     { s = Dy;  d = Dyf;  loc = base - 1048576; }
        float4 v = *(const float4*)(s + loc);
        f16x4 h = {(f16)v.x, (f16)v.y, (f16)v.z, (f16)v.w};
        *(f16x4*)(d + loc) = h;
        return;
    }
    const int bx = blockIdx.x - 1280;
    const int b  = bx >> 4;
    const int t0 = (bx & 15) * 16;
    const int wave = threadIdx.x >> 6;
    const int lane = threadIdx.x & 63;
#pragma unroll
    for (int rr = 0; rr < 4; ++rr) {
        int tloc = wave * 4 + rr;
        const float* p = emb + ((size_t)b * TT + t0 + tloc) * DD;
        float4 v = *(const float4*)(p + lane * 4);
        float s  = v.x + v.y + v.z + v.w;
        float s2 = v.x*v.x + v.y*v.y + v.z*v.z + v.w*v.w;
#pragma unroll
        for (int o = 32; o; o >>= 1) {
            s  += __shfl_xor(s,  o, 64);
            s2 += __shfl_xor(s2, o, 64);
        }
        float m   = s * (1.0f / 256.0f);
        float sc  = rsqrtf(s2 * (1.0f / 256.0f) - m * m + 1e-5f);
        sT[lane * 4 + 0][tloc] = (f16)((v.x - m) * sc);
        sT[lane * 4 + 1][tloc] = (f16)((v.y - m) * sc);
        sT[lane * 4 + 2][tloc] = (f16)((v.z - m) * sc);
        sT[lane * 4 + 3][tloc] = (f16)((v.w - m) * sc);
    }
    __syncthreads();
    int j = threadIdx.x;
    size_t o = ((size_t)b * DD + j) * TT + t0;
    *(f16x8*)(lnvTf + o)     = *(const f16x8*)&sT[j][0];
    *(f16x8*)(lnvTf + o + 8) = *(const f16x8*)&sT[j][8];
}

// ===== K2: xu = relu(emb @ Dx^T) -> f16, 64x128 tile, BK=64, + Spart =======
__launch_bounds__(256)
__global__ void k_xu(const f16* __restrict__ A, const f16* __restrict__ B,
                     f16* __restrict__ xuh, float* __restrict__ Spart) {
    const int i0 = blockIdx.y * 64, j0 = blockIdx.x * 128;
    const int t = threadIdx.x, lane = t & 63, wid = t >> 6;
    const int wr = wid >> 1, wc = wid & 1;
    const int lr = lane >> 4, lc = lane & 15;
    __shared__ __align__(16) f16 sA[2][64][72], sB[2][128][72];
    __shared__ float ssum[64][2];
    const int arow = t >> 2, akq = (t & 3) * 16;
    f32x4 acc[2][4];
    const f32x4 z4 = {0.f, 0.f, 0.f, 0.f};
#pragma unroll
    for (int fi = 0; fi < 2; ++fi)
#pragma unroll
        for (int fj = 0; fj < 4; ++fj) acc[fi][fj] = z4;

    const int NT = DD / 64;  // 4
    const f16* pa  = A + (size_t)(i0 + arow) * DD + akq;
    const f16* pb0 = B + (size_t)(j0 + arow) * DD + akq;
    const f16* pb1 = B + (size_t)(j0 + 64 + arow) * DD + akq;
    f16x8 va0  = *(const f16x8*)pa,        va1  = *(const f16x8*)(pa + 8);
    f16x8 vb00 = *(const f16x8*)pb0,       vb01 = *(const f16x8*)(pb0 + 8);
    f16x8 vb10 = *(const f16x8*)pb1,       vb11 = *(const f16x8*)(pb1 + 8);
    *(f16x8*)&sA[0][arow][akq]          = va0;
    *(f16x8*)&sA[0][arow][akq + 8]      = va1;
    *(f16x8*)&sB[0][arow][akq]          = vb00;
    *(f16x8*)&sB[0][arow][akq + 8]      = vb01;
    *(f16x8*)&sB[0][64 + arow][akq]     = vb10;
    *(f16x8*)&sB[0][64 + arow][akq + 8] = vb11;
    __syncthreads();
    int cur = 0;
    for (int kt = 0; kt < NT; ++kt) {
        if (kt + 1 < NT) {
            int ko = (kt + 1) * 64;
            va0  = *(const f16x8*)(pa + ko);   va1  = *(const f16x8*)(pa + ko + 8);
            vb00 = *(const f16x8*)(pb0 + ko);  vb01 = *(const f16x8*)(pb0 + ko + 8);
            vb10 = *(const f16x8*)(pb1 + ko);  vb11 = *(const f16x8*)(pb1 + ko + 8);
        }
#pragma unroll
        for (int ks = 0; ks < 2; ++ks) {
            f16x8 ah[2], bh[4];
#pragma unroll
            for (int fi = 0; fi < 2; ++fi)
                ah[fi] = *(const f16x8*)&sA[cur][wr * 32 + fi * 16 + lc][ks * 32 + lr * 8];
#pragma unroll
            for (int fj = 0; fj < 4; ++fj)
                bh[fj] = *(const f16x8*)&sB[cur][wc * 64 + fj * 16 + lc][ks * 32 + lr * 8];
#pragma unroll
            for (int fi = 0; fi < 2; ++fi)
#pragma unroll
                for (int fj = 0; fj < 4; ++fj)
                    acc[fi][fj] = mfma16(ah[fi], bh[fj], acc[fi][fj]);
        }
        if (kt + 1 < NT) {
            *(f16x8*)&sA[cur ^ 1][arow][akq]          = va0;
            *(f16x8*)&sA[cur ^ 1][arow][akq + 8]      = va1;
            *(f16x8*)&sB[cur ^ 1][arow][akq]          = vb00;
            *(f16x8*)&sB[cur ^ 1][arow][akq + 8]      = vb01;
            *(f16x8*)&sB[cur ^ 1][64 + arow][akq]     = vb10;
            *(f16x8*)&sB[cur ^ 1][64 + arow][akq + 8] = vb11;
            __syncthreads();
            cur ^= 1;
        }
    }
    float rs[2][4] = {};
#pragma unroll
    for (int fi = 0; fi < 2; ++fi)
#pragma unroll
        for (int fj = 0; fj < 4; ++fj) {
            f32x4 d = acc[fi][fj];
#pragma unroll
            for (int r = 0; r < 4; ++r) {
                int i = i0 + wr * 32 + fi * 16 + lr * 4 + r;
                int j = j0 + wc * 64 + fj * 16 + lc;
                float vv = fmaxf(d[r], 0.f);
                xuh[(size_t)i * NN + j] = (f16)vv;
                rs[fi][r] += vv;
            }
        }
#pragma unroll
    for (int fi = 0; fi < 2; ++fi)
#pragma unroll
        for (int r = 0; r < 4; ++r) {
            float v = rs[fi][r];
#pragma unroll
            for (int m = 1; m < 16; m <<= 1) v += __shfl_xor(v, m, 64);
            if (lc == 0) ssum[wr * 32 + fi * 16 + lr * 4 + r][wc] = v;
        }
    __syncthreads();
    if (t < 64) Spart[(size_t)blockIdx.x * ROWS + i0 + t] = ssum[t][0] + ssum[t][1];
}

// ===== K3: x-scan, 8 chunks x 32 j (64B segments), inline normalizer =======
__launch_bounds__(256)
__global__ void k_xscan(const f16* __restrict__ xuh, const float* __restrict__ Spart,
                        f16* __restrict__ xf) {
    __shared__ float Gs[8][33], Hs[8][33], Cs[8][33];
    __shared__ float sS[256], sRC[256];
    __shared__ int bad;
    const int b = blockIdx.x >> 5, jgrp = blockIdx.x & 31;
    const int tid = threadIdx.x;
    float s = 0.f;
#pragma unroll
    for (int g = 0; g < 8; ++g) s += Spart[(size_t)g * ROWS + b * TT + tid];
    if (tid == 0) bad = 0;
    sS[tid] = s;
    __syncthreads();
    float us = (tid == 0) ? s : (0.97f + s);
    if (us < 1e-12f) bad = 1;
    __syncthreads();
    if (!bad) {
        sRC[tid] = 1.0f / us;
    } else if (tid == 0) {
        float sigma = 0.f;
        for (int tt = 0; tt < TT; ++tt) {
            float u2 = fmaf(0.97f, sigma, sS[tt]);
            float r  = 1.0f / fmaxf(u2, 1e-12f);
            sRC[tt] = r;
            sigma = u2 * r;
        }
    }
    __syncthreads();

    const int ck = tid >> 5, jl = tid & 31;
    const int j  = jgrp * 32 + jl;
    const size_t base = ((size_t)b * TT + ck * 32) * NN + j;
    float xur[32], rcr[32];
#pragma unroll
    for (int i = 0; i < 32; ++i) xur[i] = (float)xuh[base + (size_t)i * NN];
#pragma unroll
    for (int i = 0; i < 32; ++i) rcr[i] = sRC[ck * 32 + i];
    float xs = 0.f, G = 1.f;
#pragma unroll
    for (int i = 0; i < 32; ++i) {
        xs = fmaf(0.97f, xs, xur[i]) * rcr[i];
        G *= 0.97f * rcr[i];
    }
    Gs[ck][jl] = G;
    Hs[ck][jl] = xs;
    __syncthreads();
    if (tid < 32) {
        float cr = 0.f;
        Cs[0][tid] = 0.f;
#pragma unroll
        for (int cc = 0; cc < 7; ++cc) {
            cr = fmaf(Gs[cc][tid], cr, Hs[cc][tid]);
            Cs[cc + 1][tid] = cr;
        }
    }
    __syncthreads();
    xs = Cs[ck][jl];
#pragma unroll
    for (int i = 0; i < 32; ++i) {
        xs = fmaf(0.97f, xs, xur[i]) * rcr[i];
        xf[base + (size_t)i * NN] = (f16)xs;
    }
}

// ===== K4: W = causal-decay mask . (X X^T), 64x64, batched, BK=64 ==========
__launch_bounds__(256)
__global__ void k_W(const f16* __restrict__ xf, f16* __restrict__ Wf) {
    const int b = blockIdx.z;
    const f16* X = xf + (size_t)b * TT * NN;
    f16* Wb = Wf + (size_t)b * TT * TT;
    const int i0 = blockIdx.y * 64, j0 = blockIdx.x * 64;
    const int t = threadIdx.x, lane = t & 63, wid = t >> 6;
    const int wr = wid >> 1, wc = wid & 1;
    const int lr = lane >> 4, lc = lane & 15;
    const float L2D = -0.043943348f;  // log2(0.97)

    if (j0 > i0) {
#pragma unroll
        for (int fi = 0; fi < 2; ++fi)
#pragma unroll
            for (int fj = 0; fj < 2; ++fj)
#pragma unroll
                for (int r = 0; r < 4; ++r) {
                    int i = i0 + wr * 32 + fi * 16 + lr * 4 + r;
                    int j = j0 + wc * 32 + fj * 16 + lc;
                    Wb[(size_t)i * TT + j] = (f16)0.f;
                }
        return;
    }

    __shared__ __align__(16) f16 sA[2][64][72], sB[2][64][72];
    const int srow = t >> 2, skq = (t & 3) * 16;
    f32x4 acc[2][2];
    const f32x4 z4 = {0.f, 0.f, 0.f, 0.f};
    acc[0][0] = z4; acc[0][1] = z4; acc[1][0] = z4; acc[1][1] = z4;

    const int NT = NN / 64;  // 16
    const f16* pa = X + (size_t)(i0 + srow) * NN + skq;
    const f16* pb = X + (size_t)(j0 + srow) * NN + skq;
    f16x8 va0 = *(const f16x8*)pa,       va1 = *(const f16x8*)(pa + 8);
    f16x8 vb0 = *(const f16x8*)pb,       vb1 = *(const f16x8*)(pb + 8);
    *(f16x8*)&sA[0][srow][skq]     = va0;
    *(f16x8*)&sA[0][srow][skq + 8] = va1;
    *(f16x8*)&sB[0][srow][skq]     = vb0;
    *(f16x8*)&sB[0][srow][skq + 8] = vb1;
    __syncthreads();
    int cur = 0;
    for (int kt = 0; kt < NT; ++kt) {
        if (kt + 1 < NT) {
            int ko = (kt + 1) * 64;
            va0 = *(const f16x8*)(pa + ko);  va1 = *(const f16x8*)(pa + ko + 8);
            vb0 = *(const f16x8*)(pb + ko);  vb1 = *(const f16x8*)(pb + ko + 8);
        }
#pragma unroll
        for (int ks = 0; ks < 2; ++ks) {
            f16x8 ah0 = *(const f16x8*)&sA[cur][wr * 32 + lc][ks * 32 + lr * 8];
            f16x8 ah1 = *(const f16x8*)&sA[cur][wr * 32 + 16 + lc][ks * 32 + lr * 8];
            f16x8 bh0 = *(const f16x8*)&sB[cur][wc * 32 + lc][ks * 32 + lr * 8];
            f16x8 bh1 = *(const f16x8*)&sB[cur][wc * 32 + 16 + lc][ks * 32 + lr * 8];
            acc[0][0] = mfma16(ah0, bh0, acc[0][0]);
            acc[0][1] = mfma16(ah0, bh1, acc[0][1]);
            acc[1][0] = mfma16(ah1, bh0, acc[1][0]);
            acc[1][1] = mfma16(ah1, bh1, acc[1][1]);
        }
        if (kt + 1 < NT) {
            *(f16x8*)&sA[cur ^ 1][srow][skq]     = va0;
            *(f16x8*)&sA[cur ^ 1][srow][skq + 8] = va1;
            *(f16x8*)&sB[cur ^ 1][srow][skq]     = vb0;
            *(f16x8*)&sB[cur ^ 1][srow][skq + 8] = vb1;
            __syncthreads();
            cur ^= 1;
        }
    }
#pragma unroll
    for (int fi = 0; fi < 2; ++fi)
#pragma unroll
        for (int fj = 0; fj < 2; ++fj) {
            f32x4 d = acc[fi][fj];
#pragma unroll
            for (int r = 0; r < 4; ++r) {
                int i = i0 + wr * 32 + fi * 16 + lr * 4 + r;
                int j = j0 + wc * 32 + fj * 16 + lc;
                float w = 0.f;
                if (j < i) w = exp2f((float)(i - 1 - j) * L2D) * d[r];
                Wb[(size_t)i * TT + j] = (f16)w;
            }
        }
}

// ===== K5: aln = LN(W @ lnv), 16-row blocks (grid 16x8 = 128) ==============
__launch_bounds__(256)
__global__ void k_aln(const f16* __restrict__ Wf, const f16* __restrict__ lnvTf,
                      f16* __restrict__ alnf) {
    const int b = blockIdx.y;
    const int i0 = blockIdx.x * 16;
    const f16* A = Wf + (size_t)b * TT * TT;
    const f16* B = lnvTf + (size_t)b * DD * TT;
    const int t = threadIdx.x, lane = t & 63, w = t >> 6;
    const int lr = lane >> 4, lc = lane & 15;
    __shared__ __align__(16) f16 sA[2][16][40], sB[2][256][40];
    __shared__ float sS[4][16], sS2[4][16];
    const int arow = t >> 2, akq = (t & 3) * 8;
    f32x4 acc[4];
    const f32x4 z4 = {0.f, 0.f, 0.f, 0.f};
#pragma unroll
    for (int f = 0; f < 4; ++f) acc[f] = z4;

    const int NT = TT / 32;  // 8
    const f16* pa = A + (size_t)(i0 + arow) * TT + akq;
    const f16* pb = B + (size_t)arow * TT + akq;
    f16x8 va;
    f16x8 vb[4];
    if (t < 64) va = *(const f16x8*)pa;
#pragma unroll
    for (int q = 0; q < 4; ++q)
        vb[q] = *(const f16x8*)(pb + (size_t)q * 64 * TT);
    if (t < 64) *(f16x8*)&sA[0][arow][akq] = va;
#pragma unroll
    for (int q = 0; q < 4; ++q)
        *(f16x8*)&sB[0][q * 64 + arow][akq] = vb[q];
    __syncthreads();
    int cur = 0;
    for (int kt = 0; kt < NT; ++kt) {
        if (kt + 1 < NT) {
            int ko = (kt + 1) * 32;
            if (t < 64) va = *(const f16x8*)(pa + ko);
#pragma unroll
            for (int q = 0; q < 4; ++q)
                vb[q] = *(const f16x8*)(pb + (size_t)q * 64 * TT + ko);
        }
        f16x8 af = *(const f16x8*)&sA[cur][lc][lr * 8];
#pragma unroll
        for (int f = 0; f < 4; ++f) {
            f16x8 bf = *(const f16x8*)&sB[cur][w * 64 + f * 16 + lc][lr * 8];
            acc[f] = mfma16(af, bf, acc[f]);
        }
        if (kt + 1 < NT) {
            if (t < 64) *(f16x8*)&sA[cur ^ 1][arow][akq] = va;
#pragma unroll
            for (int q = 0; q < 4; ++q)
                *(f16x8*)&sB[cur ^ 1][q * 64 + arow][akq] = vb[q];
            __syncthreads();
            cur ^= 1;
        }
    }
    float s[4] = {}, s2[4] = {};
#pragma unroll
    for (int f = 0; f < 4; ++f)
#pragma unroll
        for (int r = 0; r < 4; ++r) { float v = acc[f][r]; s[r] += v; s2[r] += v * v; }
#pragma unroll
    for (int m = 1; m < 16; m <<= 1)
#pragma unroll
        for (int r = 0; r < 4; ++r) {
            s[r]  += __shfl_xor(s[r],  m, 64);
            s2[r] += __shfl_xor(s2[r], m, 64);
        }
    if (lc == 0)
#pragma unroll
        for (int r = 0; r < 4; ++r) { sS[w][lr * 4 + r] = s[r]; sS2[w][lr * 4 + r] = s2[r]; }
    __syncthreads();
    float mean[4], rstd[4];
#pragma unroll
    for (int r = 0; r < 4; ++r) {
        int row = lr * 4 + r;
        float tot  = sS[0][row] + sS[1][row] + sS[2][row] + sS[3][row];
        float tot2 = sS2[0][row] + sS2[1][row] + sS2[2][row] + sS2[3][row];
        mean[r] = tot * (1.f / 256.f);
        rstd[r] = rsqrtf(tot2 * (1.f / 256.f) - mean[r] * mean[r] + 1e-5f);
    }
#pragma unroll
    for (int f = 0; f < 4; ++f)
#pragma unroll
        for (int r = 0; r < 4; ++r) {
            int i = i0 + lr * 4 + r;
            int j = w * 64 + f * 16 + lc;
            alnf[((size_t)b * TT + i) * DD + j] = (f16)((acc[f][r] - mean[r]) * rstd[r]);
        }
}

// ===== K6: y = relu(aln @ Dy^T) * x, 64x128 tile, BK=64 ====================
__launch_bounds__(256)
__global__ void k_y(const f16* __restrict__ A, const f16* __restrict__ B,
                    f16* __restrict__ yf, const f16* __restrict__ xf) {
    const int i0 = blockIdx.y * 64, j0 = blockIdx.x * 128;
    const int t = threadIdx.x, lane = t & 63, wid = t >> 6;
    const int wr = wid >> 1, wc = wid & 1;
    const int lr = lane >> 4, lc = lane & 15;
    __shared__ __align__(16) f16 sA[2][64][72], sB[2][128][72];
    const int arow = t >> 2, akq = (t & 3) * 16;
    f32x4 acc[2][4];
    const f32x4 z4 = {0.f, 0.f, 0.f, 0.f};
#pragma unroll
    for (int fi = 0; fi < 2; ++fi)
#pragma unroll
        for (int fj = 0; fj < 4; ++fj) acc[fi][fj] = z4;

    const int NT = DD / 64;  // 4
    const f16* pa  = A + (size_t)(i0 + arow) * DD + akq;
    const f16* pb0 = B + (size_t)(j0 + arow) * DD + akq;
    const f16* pb1 = B + (size_t)(j0 + 64 + arow) * DD + akq;
    f16x8 va0  = *(const f16x8*)pa,        va1  = *(const f16x8*)(pa + 8);
    f16x8 vb00 = *(const f16x8*)pb0,       vb01 = *(const f16x8*)(pb0 + 8);
    f16x8 vb10 = *(const f16x8*)pb1,       vb11 = *(const f16x8*)(pb1 + 8);
    *(f16x8*)&sA[0][arow][akq]          = va0;
    *(f16x8*)&sA[0][arow][akq + 8]      = va1;
    *(f16x8*)&sB[0][arow][akq]          = vb00;
    *(f16x8*)&sB[0][arow][akq + 8]      = vb01;
    *(f16x8*)&sB[0][64 + arow][akq]     = vb10;
    *(f16x8*)&sB[0][64 + arow][akq + 8] = vb11;
    __syncthreads();
    int cur = 0;
    for (int kt = 0; kt < NT; ++kt) {
        if (kt + 1 < NT) {
            int ko = (kt + 1) * 64;
            va0  = *(const f16x8*)(pa + ko);   va1  = *(const f16x8*)(pa + ko + 8);
            vb00 = *(const f16x8*)(pb0 + ko);  vb01 = *(const f16x8*)(pb0 + ko + 8);
            vb10 = *(const f16x8*)(pb1 + ko);  vb11 = *(const f16x8*)(pb1 + ko + 8);
        }
#pragma unroll
        for (int ks = 0; ks < 2; ++ks) {
            f16x8 ah[2], bh[4];
#pragma unroll
            for (int fi = 0; fi < 2; ++fi)
                ah[fi] = *(const f16x8*)&sA[cur][wr * 32 + fi * 16 + lc][ks * 32 + lr * 8];
#pragma unroll
            for (int fj = 0; fj < 4; ++fj)
                bh[fj] = *(const f16x8*)&sB[cur][wc * 64 + fj * 16 + lc][ks * 32 + lr * 8];
#pragma unroll
            for (int fi = 0; fi < 2; ++fi)
#pragma unroll
                for (int fj = 0; fj < 4; ++fj)
                    acc[fi][fj] = mfma16(ah[fi], bh[fj], acc[fi][fj]);
        }
        if (kt + 1 < NT) {
            *(f16x8*)&sA[cur ^ 1][arow][akq]          = va0;
            *(f16x8*)&sA[cur ^ 1][arow][akq + 8]      = va1;
            *(f16x8*)&sB[cur ^ 1][arow][akq]          = vb00;
            *(f16x8*)&sB[cur ^ 1][arow][akq + 8]      = vb01;
            *(f16x8*)&sB[cur ^ 1][64 + arow][akq]     = vb10;
            *(f16x8*)&sB[cur ^ 1][64 + arow][akq + 8] = vb11;
            __syncthreads();
            cur ^= 1;
        }
    }
#pragma unroll
    for (int fi = 0; fi < 2; ++fi)
#pragma unroll
        for (int fj = 0; fj < 4; ++fj) {
            f32x4 d = acc[fi][fj];
#pragma unroll
            for (int r = 0; r < 4; ++r) {
                int i = i0 + wr * 32 + fi * 16 + lr * 4 + r;
                int j = j0 + wc * 64 + fj * 16 + lc;
                size_t o = (size_t)i * NN + j;
                float vv = fmaxf(d[r], 0.f) * (float)xf[o];
                yf[o] = (f16)vv;
            }
        }
}

// ===== K7: vpart[z] = y @ E^T (K-half z), 64x64 tile, BK=64 ================
__launch_bounds__(256)
__global__ void k_vg(const f16* __restrict__ yf, const f16* __restrict__ Ef,
                     float* __restrict__ vpart) {
    const int z = blockIdx.z;
    float* C = vpart + (size_t)z * ROWS * DD;
    const int i0 = blockIdx.y * 64, j0 = blockIdx.x * 64;
    const int t = threadIdx.x, lane = t & 63, wid = t >> 6;
    const int wr = wid >> 1, wc = wid & 1;
    const int lr = lane >> 4, lc = lane & 15;
    __shared__ __align__(16) f16 sA[2][64][72], sB[2][64][72];
    const int srow = t >> 2, skq = (t & 3) * 16;
    f32x4 acc[2][2];
    const f32x4 z4 = {0.f, 0.f, 0.f, 0.f};
    acc[0][0] = z4; acc[0][1] = z4; acc[1][0] = z4; acc[1][1] = z4;

    const int NT = 512 / 64;  // 8
    const f16* pa = yf + (size_t)(i0 + srow) * NN + z * 512 + skq;
    const f16* pb = Ef + (size_t)(j0 + srow) * NN + z * 512 + skq;
    f16x8 va0 = *(const f16x8*)pa,       va1 = *(const f16x8*)(pa + 8);
    f16x8 vb0 = *(const f16x8*)pb,       vb1 = *(const f16x8*)(pb + 8);
    *(f16x8*)&sA[0][srow][skq]     = va0;
    *(f16x8*)&sA[0][srow][skq + 8] = va1;
    *(f16x8*)&sB[0][srow][skq]     = vb0;
    *(f16x8*)&sB[0][srow][skq + 8] = vb1;
    __syncthreads();
    int cur = 0;
    for (int kt = 0; kt < NT; ++kt) {
        if (kt + 1 < NT) {
            int ko = (kt + 1) * 64;
            va0 = *(const f16x8*)(pa + ko);  va1 = *(const f16x8*)(pa + ko + 8);
            vb0 = *(const f16x8*)(pb + ko);  vb1 = *(const f16x8*)(pb + ko + 8);
        }
#pragma unroll
        for (int ks = 0; ks < 2; ++ks) {
            f16x8 ah0 = *(const f16x8*)&sA[cur][wr * 32 + lc][ks * 32 + lr * 8];
            f16x8 ah1 = *(const f16x8*)&sA[cur][wr * 32 + 16 + lc][ks * 32 + lr * 8];
            f16x8 bh0 = *(const f16x8*)&sB[cur][wc * 32 + lc][ks * 32 + lr * 8];
            f16x8 bh1 = *(const f16x8*)&sB[cur][wc * 32 + 16 + lc][ks * 32 + lr * 8];
            acc[0][0] = mfma16(ah0, bh0, acc[0][0]);
            acc[0][1] = mfma16(ah0, bh1, acc[0][1]);
            acc[1][0] = mfma16(ah1, bh0, acc[1][0]);
            acc[1][1] = mfma16(ah1, bh1, acc[1][1]);
        }
        if (kt + 1 < NT) {
            *(f16x8*)&sA[cur ^ 1][srow][skq]     = va0;
            *(f16x8*)&sA[cur ^ 1][srow][skq + 8] = va1;
            *(f16x8*)&sB[cur ^ 1][srow][skq]     = vb0;
            *(f16x8*)&sB[cur ^ 1][srow][skq + 8] = vb1;
            __syncthreads();
            cur ^= 1;
        }
    }
#pragma unroll
    for (int fi = 0; fi < 2; ++fi)
#pragma unroll
        for (int fj = 0; fj < 2; ++fj) {
            f32x4 d = acc[fi][fj];
#pragma unroll
            for (int r = 0; r < 4; ++r) {
                int i = i0 + wr * 32 + fi * 16 + lr * 4 + r;
                int j = j0 + wc * 32 + fj * 16 + lc;
                C[(size_t)i * DD + j] = d[r];
            }
        }
}

// ===== K8: out = LN(vpart0 + vpart1) ======================================
__launch_bounds__(256)
__global__ void ln2_kernel(const float* __restrict__ in, const float* __restrict__ in2,
                           float* __restrict__ outf) {
    int wave = threadIdx.x >> 6;
    int lane = threadIdx.x & 63;
    int row  = blockIdx.x * 4 + wave;
    float4 v = *(const float4*)(in + (size_t)row * DD + lane * 4);
    float4 w = *(const float4*)(in2 + (size_t)row * DD + lane * 4);
    v.x += w.x; v.y += w.y; v.z += w.z; v.w += w.w;
    float s  = v.x + v.y + v.z + v.w;
    float s2 = v.x*v.x + v.y*v.y + v.z*v.z + v.w*v.w;
#pragma unroll
    for (int o = 32; o; o >>= 1) {
        s  += __shfl_xor(s,  o, 64);
        s2 += __shfl_xor(s2, o, 64);
    }
    float m  = s * (1.0f / 256.0f);
    float sc = rsqrtf(s2 * (1.0f / 256.0f) - m * m + 1e-5f);
    float4 o4 = {(v.x - m) * sc, (v.y - m) * sc, (v.z - m) * sc, (v.w - m) * sc};
    *(float4*)(outf + (size_t)row * DD + lane * 4) = o4;
}

extern "C" void kernel_launch(void* const* d_in, const int* in_sizes, int n_in,
                              void* d_out, int out_size, void* d_ws, size_t ws_size,
                              hipStream_t stream) {
    (void)in_sizes; (void)n_in; (void)out_size; (void)ws_size;
    const float* emb = (const float*)d_in[0];   // (B,T,d)
    const float* E   = (const float*)d_in[1];   // (d,n)
    const float* Dx  = (const float*)d_in[2];   // (n,d)
    const float* Dy  = (const float*)d_in[3];   // (n,d)
    float* out = (float*)d_out;                 // (B,T,d)

    char* wsb = (char*)d_ws;
    f16*   embf  = (f16*)(wsb + 0);          // 1 MB
    f16*   Ef    = (f16*)(wsb + 1048576);    // 512 KB
    f16*   Dxf   = (f16*)(wsb + 1572864);    // 512 KB
    f16*   Dyf   = (f16*)(wsb + 2097152);    // 512 KB
    f16*   lnvTf = (f16*)(wsb + 2621440);    // 1 MB   [b][j][t]
    f16*   xuh   = (f16*)(wsb + 3670016);    // 4 MB
    f16*   xf    = (f16*)(wsb + 7864320);    // 4 MB
    f16*   Wf    = (f16*)(wsb + 12058624);   // 1 MB
    f16*   alnf  = (f16*)(wsb + 13107200);   // 1 MB
    f16*   yf    = (f16*)(wsb + 14155776);   // 4 MB
    float* vpart = (float*)(wsb + 18350080); // 4 MB (2 x ROWS*DD)
    float* Spart = (float*)(wsb + 22544384); // 64 KB (8 x ROWS)

    // K1: f16 conversions + LN^T(emb)
    cvtln_kernel<<<1280 + ROWS / 16, 256, 0, stream>>>(
        emb, E, Dx, Dy, embf, Ef, Dxf, Dyf, lnvTf);
    // K2: xu = relu(emb @ Dx^T) -> f16 + row-sum partials, BK=64
    k_xu<<<dim3(NN / 128, ROWS / 64), 256, 0, stream>>>(embf, Dxf, xuh, Spart);
    // K3: x scan (coalesced 8x32 mapping)
    k_xscan<<<BB * 32, 256, 0, stream>>>(xuh, Spart, xf);
    // K4: W = mask . (X X^T), BK=64
    k_W<<<dim3(TT / 64, TT / 64, BB), 256, 0, stream>>>(xf, Wf);
    // K5: aln = LN(W @ lnv), 16-row blocks
    k_aln<<<dim3(TT / 16, BB), 256, 0, stream>>>(Wf, lnvTf, alnf);
    // K6: y = relu(aln @ Dy^T) * x, BK=64
    k_y<<<dim3(NN / 128, ROWS / 64), 256, 0, stream>>>(alnf, Dyf, yf, xf);
    // K7: vpart = y @ E^T split-K=2, BK=64
    k_vg<<<dim3(DD / 64, ROWS / 64, 2), 256, 0, stream>>>(yf, Ef, vpart);
    // K8: out = LN(vpart0 + vpart1)
    ln2_kernel<<<ROWS / 4, 256, 0, stream>>>(
        vpart, vpart + (size_t)ROWS * DD, out);
}